// Round 17
// baseline (369.740 us; speedup 1.0000x reference)
//
#include <hip/hip_runtime.h>
#include <hip/hip_bf16.h>
#include <stdint.h>

#define SEQ    4096
#define DMODEL 1024
#define NHEAD  16
#define HDIM   64
#define NBATCH 4
#define NBH    (NBATCH*NHEAD)     // 64
#define MTOK   (NBATCH*SEQ)       // 16384
#define FEPS   1e-6f
#define PLANE  16777216u          // 16384*1024 shorts per Q/K/V plane

typedef float f32x4 __attribute__((ext_vector_type(4)));
typedef short bf16x8 __attribute__((ext_vector_type(8)));

// ---------- workspace layout (bytes) ----------
#define XB_OFF    0u                      // 16384*1024 bf16 = 33554432
#define WQKV_OFF  33554432u               // 3072*1024 bf16  = 6291456
#define WO_OFF    39845888u               // 1024*1024 bf16  = 2097152
#define QKV_OFF   41943040u               // 3 planes x 32MB = 100663296
#define AOB_OFF   142606336u              // 16384*1024 bf16 = 33554432
#define ST_OFF    176160768u
#define KSUM_OFF  (ST_OFF)                // 4096 f32
#define QSUM_OFF  (ST_OFF + 16384u)
#define QSI_OFF   (ST_OFF + 32768u)
#define KSO_OFF   (ST_OFF + 49152u)
#define ESUM_OFF  (ST_OFF + 65536u)       // 64 f32 (padded)
#define SI_OFF    (ST_OFF + 81920u)       // 262144 f32 = 1 MB
#define SA_OFF    (SI_OFF + 1048576u)
#define KVF_OFF   (SA_OFF + 1048576u)     // 64*64*64 f32 = 1 MB
#define KVP_OFF   (KVF_OFF + 1048576u)    // 8 MB partials

#define S_VMCNT(N) asm volatile("s_waitcnt vmcnt(" #N ")" ::: "memory")
#define BARRIER() do { __builtin_amdgcn_s_barrier(); asm volatile("" ::: "memory"); } while (0)

__device__ __forceinline__ unsigned short f2bf(float f) {
  __hip_bfloat16 h = __float2bfloat16(f);
  unsigned short u; __builtin_memcpy(&u, &h, 2); return u;
}
__device__ __forceinline__ float bf2f(unsigned short u) {
  union { unsigned u; float f; } x; x.u = ((unsigned)u) << 16; return x.f;
}
__device__ __forceinline__ void decode8(uint4 r, float* o) {
  o[0] = bf2f((unsigned short)(r.x & 0xffffu)); o[1] = bf2f((unsigned short)(r.x >> 16));
  o[2] = bf2f((unsigned short)(r.y & 0xffffu)); o[3] = bf2f((unsigned short)(r.y >> 16));
  o[4] = bf2f((unsigned short)(r.z & 0xffffu)); o[5] = bf2f((unsigned short)(r.z >> 16));
  o[6] = bf2f((unsigned short)(r.w & 0xffffu)); o[7] = bf2f((unsigned short)(r.w >> 16));
}
__device__ __forceinline__ void gll(const unsigned short* g, unsigned short* l) {
  __builtin_amdgcn_global_load_lds((const __attribute__((address_space(1))) void*)g,
      (__attribute__((address_space(3))) void*)l, 16, 0, 0);
}

// ---------- fused conversions: blocks 0-1023 = W transpose, 1024+ = x convert ----------
__global__ __launch_bounds__(256) void conv_all_k(const float* __restrict__ x,
                                                  const float* __restrict__ Wq, const float* __restrict__ Wk,
                                                  const float* __restrict__ Wv, const float* __restrict__ Wo,
                                                  unsigned short* __restrict__ xb,
                                                  unsigned short* __restrict__ Wqkvt,
                                                  unsigned short* __restrict__ Wot) {
  const int bx = blockIdx.x;
  if (bx < 1024) {
    __shared__ float tile[64][65];
    const int z = bx >> 8, tl = bx & 255;
    const float* W = (z == 0) ? Wq : (z == 1) ? Wk : (z == 2) ? Wv : Wo;
    unsigned short* dst = (z < 3) ? (Wqkvt + (size_t)z * 1024u * 1024u) : Wot;
    const int n0 = (tl & 15) * 64, k0 = (tl >> 4) * 64;
    const int tx = threadIdx.x & 63, ty = threadIdx.x >> 6;
    for (int i = ty; i < 64; i += 4)
      tile[i][tx] = W[(size_t)(k0 + i) * 1024 + n0 + tx];
    __syncthreads();
    for (int i = ty; i < 64; i += 4)
      dst[(size_t)(n0 + i) * 1024 + k0 + tx] = f2bf(tile[tx][i]);
  } else {
    const int n = MTOK * DMODEL;
    int i = ((bx - 1024) * 256 + threadIdx.x) * 4;
    const int stride = (gridDim.x - 1024) * 256 * 4;
    for (; i < n; i += stride) {
      float4 v = *(const float4*)(x + i);
      ushort4 o;
      o.x = f2bf(v.x); o.y = f2bf(v.y); o.z = f2bf(v.z); o.w = f2bf(v.w);
      *(ushort4*)(xb + i) = o;
    }
  }
}

// ---------- 128x128 GEMM (gemm0 only), BK=64, 4-phase, 2 blocks/CU ----------
// Ndim=3072, bias+sigmoid epilogue, writes Q/K/V head-major planes, fused colsums.
__global__ __launch_bounds__(256, 2) void gemm128_qkv(const unsigned short* __restrict__ A,
                                                      const unsigned short* __restrict__ Bt,
                                                      const float* __restrict__ b0,
                                                      const float* __restrict__ b1,
                                                      const float* __restrict__ b2,
                                                      float* __restrict__ qsum_g,
                                                      float* __restrict__ ksum_g,
                                                      unsigned short* __restrict__ C) {
  constexpr int Kd = 1024;
  constexpr int NT = Kd >> 6;
  __shared__ unsigned short sm[8 * 4096];                // 64 KiB
  const int tid = threadIdx.x;
  const int wid = tid >> 6, lane = tid & 63;
  const int wr = wid >> 1, wc = wid & 1;

  const int gx = gridDim.x;
  const int nwg = gx * gridDim.y;
  int wg = blockIdx.y * gx + blockIdx.x;
  wg = (wg & 7) * (nwg >> 3) + (wg >> 3);
  const int n0 = (wg % gx) * 128, m0 = (wg / gx) * 128;

  const int rl = lane & 15, kob = (lane >> 4) << 4;
  const int xs2 = (rl & 7) << 3;
  const int ca0 = (kob >> 1) ^ xs2;
  const int ca1 = (32 + (kob >> 1)) ^ xs2;
  const unsigned short* ArA = sm + wr * 4096 + rl * 64 + ca0;
  const unsigned short* ArB = sm + wr * 4096 + rl * 64 + ca1;
  const unsigned short* BrA = sm + (2 + wc) * 4096 + rl * 64 + ca0;
  const unsigned short* BrB = sm + (2 + wc) * 4096 + rl * 64 + ca1;

  const int srow = tid >> 3;                             // 0..31
  const int scol = (((tid & 7) * 16) ^ ((srow & 7) << 4)) >> 1;
  const unsigned short* gA0 = A + (size_t)(m0 + srow) * Kd + scol;
  const unsigned short* gA1 = gA0 + 64 * Kd;
  const unsigned short* gB0 = Bt + (size_t)(n0 + srow) * Kd + scol;
  const unsigned short* gB1 = gB0 + 64 * Kd;
  unsigned short* ldst = sm + tid * 8;

  f32x4 acc[4][4];
#pragma unroll
  for (int i = 0; i < 4; ++i)
#pragma unroll
    for (int j = 0; j < 4; ++j) acc[i][j] = (f32x4){0.f, 0.f, 0.f, 0.f};

#define STG4(g, R, T) do { \
    gll((g) + (T) * 64, ldst + (R) * 4096); \
    gll((g) + 32 * Kd + (T) * 64, ldst + (R) * 4096 + 2048); } while (0)

  STG4(gA0, 0, 0); STG4(gA1, 1, 0);
  STG4(gB0, 2, 0); STG4(gB1, 3, 0);
  STG4(gA0, 4, 1); STG4(gA1, 5, 1);
  S_VMCNT(4);
  BARRIER();

#define KB4(U, BUF) do { \
    constexpr int BO = (BUF) * 16384; \
    bf16x8 a01[2][2], a23[2][2], b01[2][2], b23[2][2]; \
    _Pragma("unroll") for (int m = 0; m < 2; ++m) { \
      a01[m][0] = *(const bf16x8*)(ArA + BO + m * 1024); \
      a01[m][1] = *(const bf16x8*)(ArB + BO + m * 1024); } \
    _Pragma("unroll") for (int n = 0; n < 2; ++n) { \
      b01[n][0] = *(const bf16x8*)(BrA + BO + n * 1024); \
      b01[n][1] = *(const bf16x8*)(BrB + BO + n * 1024); } \
    if ((U) + 1 < NT) STG4(gB0, (!(BUF)) * 4 + 2, (U) + 1); \
    BARRIER(); \
    __builtin_amdgcn_s_setprio(1); \
    _Pragma("unroll") for (int m = 0; m < 2; ++m) \
      _Pragma("unroll") for (int n = 0; n < 2; ++n) { \
        acc[m][n] = __builtin_amdgcn_mfma_f32_16x16x32_bf16(a01[m][0], b01[n][0], acc[m][n], 0, 0, 0); \
        acc[m][n] = __builtin_amdgcn_mfma_f32_16x16x32_bf16(a01[m][1], b01[n][1], acc[m][n], 0, 0, 0); } \
    __builtin_amdgcn_s_setprio(0); \
    BARRIER(); \
    _Pragma("unroll") for (int m = 0; m < 2; ++m) { \
      a23[m][0] = *(const bf16x8*)(ArA + BO + (2 + m) * 1024); \
      a23[m][1] = *(const bf16x8*)(ArB + BO + (2 + m) * 1024); } \
    if ((U) + 1 < NT) STG4(gB1, (!(BUF)) * 4 + 3, (U) + 1); \
    BARRIER(); \
    __builtin_amdgcn_s_setprio(1); \
    _Pragma("unroll") for (int m = 0; m < 2; ++m) \
      _Pragma("unroll") for (int n = 0; n < 2; ++n) { \
        acc[2 + m][n] = __builtin_amdgcn_mfma_f32_16x16x32_bf16(a23[m][0], b01[n][0], acc[2 + m][n], 0, 0, 0); \
        acc[2 + m][n] = __builtin_amdgcn_mfma_f32_16x16x32_bf16(a23[m][1], b01[n][1], acc[2 + m][n], 0, 0, 0); } \
    __builtin_amdgcn_s_setprio(0); \
    BARRIER(); \
    _Pragma("unroll") for (int n = 0; n < 2; ++n) { \
      b23[n][0] = *(const bf16x8*)(BrA + BO + (2 + n) * 1024); \
      b23[n][1] = *(const bf16x8*)(BrB + BO + (2 + n) * 1024); } \
    if ((U) + 2 < NT) STG4(gA0, (BUF) * 4, (U) + 2); \
    BARRIER(); \
    __builtin_amdgcn_s_setprio(1); \
    _Pragma("unroll") for (int m = 0; m < 2; ++m) \
      _Pragma("unroll") for (int n = 0; n < 2; ++n) { \
        acc[2 + m][2 + n] = __builtin_amdgcn_mfma_f32_16x16x32_bf16(a23[m][0], b23[n][0], acc[2 + m][2 + n], 0, 0, 0); \
        acc[2 + m][2 + n] = __builtin_amdgcn_mfma_f32_16x16x32_bf16(a23[m][1], b23[n][1], acc[2 + m][2 + n], 0, 0, 0); } \
    __builtin_amdgcn_s_setprio(0); \
    BARRIER(); \
    if ((U) + 2 < NT) STG4(gA1, (BUF) * 4 + 1, (U) + 2); \
    BARRIER(); \
    __builtin_amdgcn_s_setprio(1); \
    _Pragma("unroll") for (int m = 0; m < 2; ++m) \
      _Pragma("unroll") for (int n = 0; n < 2; ++n) { \
        acc[m][2 + n] = __builtin_amdgcn_mfma_f32_16x16x32_bf16(a01[m][0], b23[n][0], acc[m][2 + n], 0, 0, 0); \
        acc[m][2 + n] = __builtin_amdgcn_mfma_f32_16x16x32_bf16(a01[m][1], b23[n][1], acc[m][2 + n], 0, 0, 0); } \
    __builtin_amdgcn_s_setprio(0); \
    if ((U) + 2 < NT) { S_VMCNT(4); } else { S_VMCNT(0); } \
    BARRIER(); \
  } while (0)

  for (int u = 0; u < NT; u += 2) {
    KB4(u, 0);
    KB4(u + 1, 1);
  }
#undef KB4
#undef STG4

  // ---- epilogue: bias + sigmoid + head-major plane scatter + colsums ----
  const int cr = (lane >> 4) * 4, cc = lane & 15;
  float cs[4] = {0.f, 0.f, 0.f, 0.f};
#pragma unroll
  for (int m = 0; m < 4; ++m)
#pragma unroll
    for (int n = 0; n < 4; ++n)
#pragma unroll
      for (int rr = 0; rr < 4; ++rr) {
        const int gr = m0 + wr * 64 + m * 16 + cr + rr;
        const int gc = n0 + wc * 64 + n * 16 + cc;
        float v = acc[m][n][rr];
        const float bias = (gc < 1024) ? b0[gc] : ((gc < 2048) ? b1[gc - 1024] : b2[gc - 2048]);
        v += bias;
        if (gc < 2048) v = 1.f / (1.f + __expf(-v));
        cs[n] += v;
        // plane=gc>>10, bh=(gr>>12)*16+((gc>>6)&15), l=gr&4095, d=gc&63
        const size_t addr = (size_t)(gc >> 10) * PLANE +
                            ((size_t)(((gr >> 12) << 4) | ((gc >> 6) & 15)) * 4096 + (gr & 4095)) * 64 +
                            (gc & 63);
        C[addr] = f2bf(v);
      }
  if (n0 < 2048) {
#pragma unroll
    for (int n = 0; n < 4; ++n) {
      cs[n] += __shfl_xor(cs[n], 16);
      cs[n] += __shfl_xor(cs[n], 32);
    }
    if (lane < 16) {
      const int b = m0 >> 12;
#pragma unroll
      for (int n = 0; n < 4; ++n) {
        const int gc = n0 + wc * 64 + n * 16 + lane;
        const int h = (gc & 1023) >> 6, d = gc & 63;
        float* tgt = (gc < 1024) ? qsum_g : ksum_g;
        atomicAdd(&tgt[((b << 4) + h) * 64 + d], cs[n]);
      }
    }
  }
}

// ---------- 256x256 GEMM (gemm1 only): fp32 row-major out + bias ----------
__global__ __launch_bounds__(512, 2) void gemm8p_o(const unsigned short* __restrict__ A,
                                                   const unsigned short* __restrict__ Bt,
                                                   const float* __restrict__ b0,
                                                   float* __restrict__ C) {
  constexpr int Kd = 1024;
  constexpr int NT = Kd >> 6;
  __shared__ unsigned short sm[8 * 8192];                // 128 KiB
  const int tid = threadIdx.x;
  const int wid = tid >> 6, lane = tid & 63;
  const int wr = wid >> 2, wc = wid & 3;

  const int gx = gridDim.x;
  const int nwg = gx * gridDim.y;
  int wg = blockIdx.y * gx + blockIdx.x;
  wg = (wg & 7) * (nwg >> 3) + (wg >> 3);
  const int n0 = (wg % gx) * 256, m0 = (wg / gx) * 256;

  const int rl = lane & 15, kob = (lane >> 4) << 4;
  const int xs2 = (rl & 7) << 3;
  const int ca0 = (kob >> 1) ^ xs2;
  const int ca1 = (32 + (kob >> 1)) ^ xs2;
  const int brow0 = (wc & 1) * 64;
  const unsigned short* ArA = sm + wr * 8192 + rl * 64 + ca0;
  const unsigned short* ArB = sm + wr * 8192 + rl * 64 + ca1;
  const unsigned short* BrA = sm + (2 + (wc >> 1)) * 8192 + (brow0 + rl) * 64 + ca0;
  const unsigned short* BrB = sm + (2 + (wc >> 1)) * 8192 + (brow0 + rl) * 64 + ca1;

  const int srow = tid >> 3;
  const int scol = (((tid & 7) * 16) ^ ((srow & 7) << 4)) >> 1;
  const unsigned short* gA0 = A + (size_t)(m0 + srow) * Kd + scol;
  const unsigned short* gA1 = gA0 + 64 * Kd;
  const unsigned short* gA2 = gA0 + 128 * Kd;
  const unsigned short* gA3 = gA0 + 192 * Kd;
  const unsigned short* gB0 = Bt + (size_t)(n0 + srow) * Kd + scol;
  const unsigned short* gB1 = gB0 + 64 * Kd;
  const unsigned short* gB2 = gB0 + 128 * Kd;
  const unsigned short* gB3 = gB0 + 192 * Kd;
  unsigned short* ldst = sm + tid * 8;

  f32x4 acc[8][4];
#pragma unroll
  for (int i = 0; i < 8; ++i)
#pragma unroll
    for (int j = 0; j < 4; ++j) acc[i][j] = (f32x4){0.f, 0.f, 0.f, 0.f};

#define STG(g0, g1, R, T) do { \
    gll((g0) + (T) * 64, ldst + (R) * 8192); \
    gll((g1) + (T) * 64, ldst + (R) * 8192 + 4096); } while (0)

  STG(gA0, gA1, 0, 0); STG(gA2, gA3, 1, 0);
  STG(gB0, gB1, 2, 0); STG(gB2, gB3, 3, 0);
  STG(gA0, gA1, 4, 1); STG(gA2, gA3, 5, 1);
  S_VMCNT(4);
  BARRIER();

#define KBODY(U, BUF) do { \
    constexpr int BO = (BUF) * 32768; \
    bf16x8 a0[4][2], a1[4][2], b01[2][2], b23[2][2]; \
    _Pragma("unroll") for (int m = 0; m < 4; ++m) { \
      a0[m][0] = *(const bf16x8*)(ArA + BO + m * 1024); \
      a0[m][1] = *(const bf16x8*)(ArB + BO + m * 1024); } \
    _Pragma("unroll") for (int n = 0; n < 2; ++n) { \
      b01[n][0] = *(const bf16x8*)(BrA + BO + n * 1024); \
      b01[n][1] = *(const bf16x8*)(BrB + BO + n * 1024); } \
    if ((U) + 1 < NT) STG(gB0, gB1, (!(BUF)) * 4 + 2, (U) + 1); \
    BARRIER(); \
    __builtin_amdgcn_s_setprio(1); \
    _Pragma("unroll") for (int m = 0; m < 4; ++m) \
      _Pragma("unroll") for (int n = 0; n < 2; ++n) { \
        acc[m][n] = __builtin_amdgcn_mfma_f32_16x16x32_bf16(a0[m][0], b01[n][0], acc[m][n], 0, 0, 0); \
        acc[m][n] = __builtin_amdgcn_mfma_f32_16x16x32_bf16(a0[m][1], b01[n][1], acc[m][n], 0, 0, 0); } \
    __builtin_amdgcn_s_setprio(0); \
    BARRIER(); \
    _Pragma("unroll") for (int m = 0; m < 4; ++m) { \
      a1[m][0] = *(const bf16x8*)(ArA + BO + 4096 + m * 1024); \
      a1[m][1] = *(const bf16x8*)(ArB + BO + 4096 + m * 1024); } \
    if ((U) + 1 < NT) STG(gB2, gB3, (!(BUF)) * 4 + 3, (U) + 1); \
    BARRIER(); \
    __builtin_amdgcn_s_setprio(1); \
    _Pragma("unroll") for (int m = 0; m < 4; ++m) \
      _Pragma("unroll") for (int n = 0; n < 2; ++n) { \
        acc[4 + m][n] = __builtin_amdgcn_mfma_f32_16x16x32_bf16(a1[m][0], b01[n][0], acc[4 + m][n], 0, 0, 0); \
        acc[4 + m][n] = __builtin_amdgcn_mfma_f32_16x16x32_bf16(a1[m][1], b01[n][1], acc[4 + m][n], 0, 0, 0); } \
    __builtin_amdgcn_s_setprio(0); \
    BARRIER(); \
    _Pragma("unroll") for (int n = 0; n < 2; ++n) { \
      b23[n][0] = *(const bf16x8*)(BrA + BO + (2 + n) * 1024); \
      b23[n][1] = *(const bf16x8*)(BrB + BO + (2 + n) * 1024); } \
    if ((U) + 2 < NT) STG(gA0, gA1, (BUF) * 4, (U) + 2); \
    BARRIER(); \
    __builtin_amdgcn_s_setprio(1); \
    _Pragma("unroll") for (int m = 0; m < 4; ++m) \
      _Pragma("unroll") for (int n = 0; n < 2; ++n) { \
        acc[4 + m][2 + n] = __builtin_amdgcn_mfma_f32_16x16x32_bf16(a1[m][0], b23[n][0], acc[4 + m][2 + n], 0, 0, 0); \
        acc[4 + m][2 + n] = __builtin_amdgcn_mfma_f32_16x16x32_bf16(a1[m][1], b23[n][1], acc[4 + m][2 + n], 0, 0, 0); } \
    __builtin_amdgcn_s_setprio(0); \
    BARRIER(); \
    if ((U) + 2 < NT) STG(gA2, gA3, (BUF) * 4 + 1, (U) + 2); \
    BARRIER(); \
    __builtin_amdgcn_s_setprio(1); \
    _Pragma("unroll") for (int m = 0; m < 4; ++m) \
      _Pragma("unroll") for (int n = 0; n < 2; ++n) { \
        acc[m][2 + n] = __builtin_amdgcn_mfma_f32_16x16x32_bf16(a0[m][0], b23[n][0], acc[m][2 + n], 0, 0, 0); \
        acc[m][2 + n] = __builtin_amdgcn_mfma_f32_16x16x32_bf16(a0[m][1], b23[n][1], acc[m][2 + n], 0, 0, 0); } \
    __builtin_amdgcn_s_setprio(0); \
    if ((U) + 2 < NT) { S_VMCNT(4); } else { S_VMCNT(0); } \
    BARRIER(); \
  } while (0)

  for (int u = 0; u < NT; u += 2) {
    KBODY(u, 0);
    KBODY(u + 1, 1);
  }
#undef KBODY
#undef STG

  const int cr = (lane >> 4) * 4, cc = lane & 15;
#pragma unroll
  for (int m = 0; m < 8; ++m)
#pragma unroll
    for (int n = 0; n < 4; ++n)
#pragma unroll
      for (int rr = 0; rr < 4; ++rr) {
        const int gr = m0 + wr * 128 + m * 16 + cr + rr;
        const int gc = n0 + wc * 64 + n * 16 + cc;
        C[(size_t)gr * 1024 + gc] = acc[m][n][rr] + b0[gc];
      }
}

// ---------- flow statistics (head-major planes: fully streaming reads) ----------
__global__ __launch_bounds__(256) void flow1_k(const unsigned short* __restrict__ Qp,
                                               const unsigned short* __restrict__ Kp,
                                               const float* __restrict__ ksum, const float* __restrict__ qsum,
                                               float* __restrict__ si, float* __restrict__ qsi,
                                               float* __restrict__ kso) {
  const int bh = blockIdx.x >> 3, c = blockIdx.x & 7;
  const int w = threadIdx.x >> 6, lane = threadIdx.x & 63;
  const float ks = ksum[bh * 64 + lane] + FEPS;
  const float qs = qsum[bh * 64 + lane] + FEPS;
  const size_t hb = (size_t)bh * 262144 + lane;
  float qsi_acc = 0.f, kso_acc = 0.f;
  const int l0 = c * 512 + w * 128;
  for (int l = l0; l < l0 + 128; l += 4) {
    float qv[4], kvv[4], dq[4], dk[4];
#pragma unroll
    for (int u = 0; u < 4; ++u) {
      const size_t off = hb + (size_t)(l + u) * 64;
      qv[u] = bf2f(Qp[off]);
      kvv[u] = bf2f(Kp[off]);
      dq[u] = (qv[u] + FEPS) * ks;
      dk[u] = (kvv[u] + FEPS) * qs;
    }
#pragma unroll
    for (int m = 1; m < 64; m <<= 1)
#pragma unroll
      for (int u = 0; u < 4; ++u) { dq[u] += __shfl_xor(dq[u], m); dk[u] += __shfl_xor(dk[u], m); }
#pragma unroll
    for (int u = 0; u < 4; ++u) {
      const float siv = 1.f / dq[u], sov = 1.f / dk[u];
      if (lane == 0) si[(size_t)bh * SEQ + l + u] = siv;
      qsi_acc += qv[u] * siv;
      kso_acc += kvv[u] * sov;
    }
  }
  atomicAdd(&qsi[bh * 64 + lane], qsi_acc);
  atomicAdd(&kso[bh * 64 + lane], kso_acc);
}

// fused: sink_allocation + ee (LDS) + esum, then kv partial for the same 512 rows
__global__ __launch_bounds__(256) void flow2kv_k(const unsigned short* __restrict__ Qp,
                                                 const unsigned short* __restrict__ Kp,
                                                 const unsigned short* __restrict__ Vp,
                                                 const float* __restrict__ qsi, const float* __restrict__ kso,
                                                 float* __restrict__ sa, float* __restrict__ esum,
                                                 float* __restrict__ kvp) {
  const int bh = blockIdx.x >> 3, c = blockIdx.x & 7;
  __shared__ float eel[512];
  __shared__ float kch[32][64];
  __shared__ float vch[32][64];
  const int t = threadIdx.x;
  const int w = t >> 6, lane = t & 63;
  const size_t hb = (size_t)bh * 262144;

  {
    const float kov = kso[bh * 64 + lane] + FEPS;
    const float qiv = qsi[bh * 64 + lane] + FEPS;
    const size_t base = hb + lane;
    float es = 0.f;
    const int l0 = c * 512 + w * 128;
    for (int l = l0; l < l0 + 128; l += 4) {
      float ds[4], dr[4];
#pragma unroll
      for (int u = 0; u < 4; ++u) {
        const size_t off = base + (size_t)(l + u) * 64;
        ds[u] = (bf2f(Qp[off]) + FEPS) * kov;
        dr[u] = (bf2f(Kp[off]) + FEPS) * qiv;
      }
#pragma unroll
      for (int m = 1; m < 64; m <<= 1)
#pragma unroll
        for (int u = 0; u < 4; ++u) { ds[u] += __shfl_xor(ds[u], m); dr[u] += __shfl_xor(dr[u], m); }
#pragma unroll
      for (int u = 0; u < 4; ++u) {
        const float sig = 1.f / (1.f + __expf(-ds[u]));
        const float cse = fminf(1.f, fmaxf(-1.f, dr[u]));
        const float e = __expf(cse);
        if (lane == 0) { sa[(size_t)bh * SEQ + l + u] = sig; eel[l - c * 512 + u] = e; }
        es += e;
      }
    }
    if (lane == 0) atomicAdd(&esum[bh], es);
  }
  __syncthreads();

  const int sl = t >> 3, sd = (t & 7) * 8;
  const int d1 = (t >> 4) * 4, d2 = (t & 15) * 4;
  float acc[4][4] = {};
  for (int ch = 0; ch < 16; ++ch) {
    const int lloc = ch * 32 + sl;
    const size_t off = hb + (size_t)(c * 512 + lloc) * 64 + sd;
    const uint4 kr = *(const uint4*)(Kp + off);
    const uint4 vr = *(const uint4*)(Vp + off);
    const float cmp = eel[lloc];
    float kd[8], vd[8];
    decode8(kr, kd); decode8(vr, vd);
    __syncthreads();
    *(f32x4*)&kch[sl][sd]     = (f32x4){kd[0], kd[1], kd[2], kd[3]};
    *(f32x4*)&kch[sl][sd + 4] = (f32x4){kd[4], kd[5], kd[6], kd[7]};
    *(f32x4*)&vch[sl][sd]     = (f32x4){vd[0] * cmp, vd[1] * cmp, vd[2] * cmp, vd[3] * cmp};
    *(f32x4*)&vch[sl][sd + 4] = (f32x4){vd[4] * cmp, vd[5] * cmp, vd[6] * cmp, vd[7] * cmp};
    __syncthreads();
    for (int l = 0; l < 32; ++l) {
      const f32x4 ka = *(const f32x4*)&kch[l][d1];
      const f32x4 vb = *(const f32x4*)&vch[l][d2];
#pragma unroll
      for (int i = 0; i < 4; ++i)
#pragma unroll
        for (int j = 0; j < 4; ++j) acc[i][j] += ka[i] * vb[j];
    }
    __syncthreads();
  }
  float* dst = kvp + (size_t)blockIdx.x * 4096;
#pragma unroll
  for (int i = 0; i < 4; ++i)
    *(f32x4*)&dst[(d1 + i) * 64 + d2] = (f32x4){acc[i][0], acc[i][1], acc[i][2], acc[i][3]};
}

__global__ __launch_bounds__(256) void kvred_k(const float* __restrict__ kvp,
                                               const float* __restrict__ esum,
                                               float* __restrict__ kvf) {
  const int idx = blockIdx.x * 256 + threadIdx.x;
  const int bh = idx >> 12, e = idx & 4095;
  const float Ls = 4096.f / esum[bh];
  float s = 0.f;
#pragma unroll
  for (int cN = 0; cN < 8; ++cN) s += kvp[((size_t)(bh * 8 + cN) << 12) + e];
  kvf[idx] = s * Ls;
}

// out = (q*si)@kv * sa -> bf16 AOb token-major head-merged. grid NBH*16.
__global__ __launch_bounds__(256) void outk_k(const unsigned short* __restrict__ Qp,
                                              const float* __restrict__ kvf, const float* __restrict__ si,
                                              const float* __restrict__ sa,
                                              unsigned short* __restrict__ AOb) {
  const int bh = blockIdx.x >> 4, lc = blockIdx.x & 15;
  const int b = bh >> 4, h = bh & 15;
  __shared__ float kvs[4096];
  __shared__ float qs_[64 * 128];
  const int t = threadIdx.x;
  for (int i = t; i < 1024; i += 256)
    *(f32x4*)&kvs[i * 4] = *(const f32x4*)&kvf[(size_t)bh * 4096 + i * 4];
  const size_t hb = (size_t)bh * 262144;
  const int lb = (t >> 4) * 8, d2 = (t & 15) * 4;
  const int sl = t & 127, sd0 = (t >> 7) * 8;
  for (int sub = 0; sub < 2; ++sub) {
    const int l0 = lc * 256 + sub * 128;
    __syncthreads();
#pragma unroll
    for (int p = 0; p < 4; ++p) {
      const int d0 = sd0 + p * 16;
      const uint4 raw = *(const uint4*)(Qp + hb + (size_t)(l0 + sl) * 64 + d0);
      float qd[8]; decode8(raw, qd);
#pragma unroll
      for (int i = 0; i < 8; ++i) qs_[(d0 + i) * 128 + sl] = qd[i];
    }
    __syncthreads();
    float acc[8][4] = {};
    for (int dd = 0; dd < 64; ++dd) {
      const f32x4 kvv = *(const f32x4*)&kvs[dd * 64 + d2];
      const f32x4 qa = *(const f32x4*)&qs_[dd * 128 + lb];
      const f32x4 qb = *(const f32x4*)&qs_[dd * 128 + lb + 4];
#pragma unroll
      for (int i = 0; i < 4; ++i)
#pragma unroll
        for (int j = 0; j < 4; ++j) { acc[i][j] += qa[i] * kvv[j]; acc[i + 4][j] += qb[i] * kvv[j]; }
    }
#pragma unroll
    for (int i = 0; i < 8; ++i) {
      const int l = l0 + lb + i;
      const size_t sidx = (size_t)bh * SEQ + l;
      const float sc = si[sidx] * sa[sidx];
      ushort4 o;
      o.x = f2bf(acc[i][0] * sc); o.y = f2bf(acc[i][1] * sc);
      o.z = f2bf(acc[i][2] * sc); o.w = f2bf(acc[i][3] * sc);
      *(ushort4*)(AOb + (size_t)(b * SEQ + l) * 1024 + h * 64 + d2) = o;
    }
  }
}

extern "C" void kernel_launch(void* const* d_in, const int* in_sizes, int n_in,
                              void* d_out, int out_size, void* d_ws, size_t ws_size,
                              hipStream_t stream) {
  const float* x  = (const float*)d_in[0];
  const float* Wq = (const float*)d_in[1];
  const float* bq = (const float*)d_in[2];
  const float* Wk = (const float*)d_in[3];
  const float* bk = (const float*)d_in[4];
  const float* Wv = (const float*)d_in[5];
  const float* bv = (const float*)d_in[6];
  const float* Wo = (const float*)d_in[7];
  const float* bo = (const float*)d_in[8];
  char* ws = (char*)d_ws;
  unsigned short* Xb    = (unsigned short*)(ws + XB_OFF);
  unsigned short* Wqkvt = (unsigned short*)(ws + WQKV_OFF);
  unsigned short* Wot   = (unsigned short*)(ws + WO_OFF);
  unsigned short* QKV   = (unsigned short*)(ws + QKV_OFF);
  unsigned short* AOb   = (unsigned short*)(ws + AOB_OFF);
  unsigned short* Qp = QKV;
  unsigned short* Kp = QKV + PLANE;
  unsigned short* Vp = QKV + 2 * PLANE;
  float* ksum = (float*)(ws + KSUM_OFF);
  float* qsum = (float*)(ws + QSUM_OFF);
  float* qsi  = (float*)(ws + QSI_OFF);
  float* kso  = (float*)(ws + KSO_OFF);
  float* esum = (float*)(ws + ESUM_OFF);
  float* si   = (float*)(ws + SI_OFF);
  float* sa   = (float*)(ws + SA_OFF);
  float* kvf  = (float*)(ws + KVF_OFF);
  float* kvp  = (float*)(ws + KVP_OFF);

  (void)hipMemsetAsync(ws + ST_OFF, 0, 81920, stream);  // zero small atomic accumulators
  conv_all_k<<<3072, 256, 0, stream>>>(x, Wq, Wk, Wv, Wo, Xb, Wqkvt, Wot);
  gemm128_qkv<<<dim3(24, 128), 256, 0, stream>>>(Xb, Wqkvt, bq, bk, bv, qsum, ksum, QKV);
  flow1_k<<<NBH * 8, 256, 0, stream>>>(Qp, Kp, ksum, qsum, si, qsi, kso);
  flow2kv_k<<<NBH * 8, 256, 0, stream>>>(Qp, Kp, Vp, qsi, kso, sa, esum, kvp);
  kvred_k<<<1024, 256, 0, stream>>>(kvp, esum, kvf);
  outk_k<<<NBH * 16, 256, 0, stream>>>(Qp, kvf, si, sa, AOb);
  gemm8p_o<<<dim3(4, 64), 512, 0, stream>>>(AOb, Wot, bo, (float*)d_out);
}

// Round 18
// 349.328 us; speedup vs baseline: 1.0584x; 1.0584x over previous
//
#include <hip/hip_runtime.h>
#include <hip/hip_bf16.h>
#include <stdint.h>

#define SEQ    4096
#define DMODEL 1024
#define NHEAD  16
#define HDIM   64
#define NBATCH 4
#define NBH    (NBATCH*NHEAD)     // 64
#define MTOK   (NBATCH*SEQ)       // 16384
#define FEPS   1e-6f
#define PLANE  16777216u          // 16384*1024 shorts per Q/K/V plane

typedef float f32x4 __attribute__((ext_vector_type(4)));
typedef short bf16x8 __attribute__((ext_vector_type(8)));

// ---------- workspace layout (bytes) ----------
#define XB_OFF    0u                      // 16384*1024 bf16 = 33554432
#define WQKV_OFF  33554432u               // 3072*1024 bf16  = 6291456
#define WO_OFF    39845888u               // 1024*1024 bf16  = 2097152
#define QKV_OFF   41943040u               // 3 planes x 32MB = 100663296
#define AOB_OFF   142606336u              // 16384*1024 bf16 = 33554432
#define ST_OFF    176160768u
#define KSUM_OFF  (ST_OFF)                // 4096 f32
#define QSUM_OFF  (ST_OFF + 16384u)
#define QSI_OFF   (ST_OFF + 32768u)
#define KSO_OFF   (ST_OFF + 49152u)
#define ESUM_OFF  (ST_OFF + 65536u)       // 64 f32 (padded)
#define SI_OFF    (ST_OFF + 81920u)       // 262144 f32 = 1 MB
#define SA_OFF    (SI_OFF + 1048576u)
#define KVF_OFF   (SA_OFF + 1048576u)     // 64*64*64 f32 = 1 MB
#define KVP_OFF   (KVF_OFF + 1048576u)    // 8 MB partials

#define S_VMCNT(N) asm volatile("s_waitcnt vmcnt(" #N ")" ::: "memory")
#define BARRIER() do { __builtin_amdgcn_s_barrier(); asm volatile("" ::: "memory"); } while (0)

__device__ __forceinline__ unsigned short f2bf(float f) {
  __hip_bfloat16 h = __float2bfloat16(f);
  unsigned short u; __builtin_memcpy(&u, &h, 2); return u;
}
__device__ __forceinline__ float bf2f(unsigned short u) {
  union { unsigned u; float f; } x; x.u = ((unsigned)u) << 16; return x.f;
}
__device__ __forceinline__ void decode8(uint4 r, float* o) {
  o[0] = bf2f((unsigned short)(r.x & 0xffffu)); o[1] = bf2f((unsigned short)(r.x >> 16));
  o[2] = bf2f((unsigned short)(r.y & 0xffffu)); o[3] = bf2f((unsigned short)(r.y >> 16));
  o[4] = bf2f((unsigned short)(r.z & 0xffffu)); o[5] = bf2f((unsigned short)(r.z >> 16));
  o[6] = bf2f((unsigned short)(r.w & 0xffffu)); o[7] = bf2f((unsigned short)(r.w >> 16));
}
__device__ __forceinline__ void gll(const unsigned short* g, unsigned short* l) {
  __builtin_amdgcn_global_load_lds((const __attribute__((address_space(1))) void*)g,
      (__attribute__((address_space(3))) void*)l, 16, 0, 0);
}

// ---------- fused conversions: blocks 0-1023 = W transpose, 1024+ = x convert ----------
__global__ __launch_bounds__(256) void conv_all_k(const float* __restrict__ x,
                                                  const float* __restrict__ Wq, const float* __restrict__ Wk,
                                                  const float* __restrict__ Wv, const float* __restrict__ Wo,
                                                  unsigned short* __restrict__ xb,
                                                  unsigned short* __restrict__ Wqkvt,
                                                  unsigned short* __restrict__ Wot) {
  const int bx = blockIdx.x;
  if (bx < 1024) {
    __shared__ float tile[64][65];
    const int z = bx >> 8, tl = bx & 255;
    const float* W = (z == 0) ? Wq : (z == 1) ? Wk : (z == 2) ? Wv : Wo;
    unsigned short* dst = (z < 3) ? (Wqkvt + (size_t)z * 1024u * 1024u) : Wot;
    const int n0 = (tl & 15) * 64, k0 = (tl >> 4) * 64;
    const int tx = threadIdx.x & 63, ty = threadIdx.x >> 6;
    for (int i = ty; i < 64; i += 4)
      tile[i][tx] = W[(size_t)(k0 + i) * 1024 + n0 + tx];
    __syncthreads();
    for (int i = ty; i < 64; i += 4)
      dst[(size_t)(n0 + i) * 1024 + k0 + tx] = f2bf(tile[tx][i]);
  } else {
    const int n = MTOK * DMODEL;
    int i = ((bx - 1024) * 256 + threadIdx.x) * 4;
    const int stride = (gridDim.x - 1024) * 256 * 4;
    for (; i < n; i += stride) {
      float4 v = *(const float4*)(x + i);
      ushort4 o;
      o.x = f2bf(v.x); o.y = f2bf(v.y); o.z = f2bf(v.z); o.w = f2bf(v.w);
      *(ushort4*)(xb + i) = o;
    }
  }
}

// ---------- 256x256 GEMM, K=1024, BK=64, 4-phase/K-tile, single counted vmcnt ----------
// MODE 0: N=3072, bias+sigmoid epilogue, writes Q/K/V head-major planes
//         [bh][l][64] bf16 (plane = gc>>10), fused q/k per-column sums.
// MODE 1: N=1024, bias b0, fp32 row-major out.
template <int MODE>
__global__ __launch_bounds__(512, 2) void gemm8p(const unsigned short* __restrict__ A,
                                                 const unsigned short* __restrict__ Bt,
                                                 const float* __restrict__ b0,
                                                 const float* __restrict__ b1,
                                                 const float* __restrict__ b2,
                                                 float* __restrict__ qsum_g,
                                                 float* __restrict__ ksum_g,
                                                 void* __restrict__ C, int Ndim) {
  constexpr int Kd = 1024;
  constexpr int NT = Kd >> 6;
  __shared__ unsigned short sm[8 * 8192];                // 128 KiB
  const int tid = threadIdx.x;
  const int wid = tid >> 6, lane = tid & 63;
  const int wr = wid >> 2, wc = wid & 3;

  const int gx = gridDim.x;
  const int nwg = gx * gridDim.y;
  int wg = blockIdx.y * gx + blockIdx.x;
  wg = (wg & 7) * (nwg >> 3) + (wg >> 3);
  const int n0 = (wg % gx) * 256, m0 = (wg / gx) * 256;

  const int rl = lane & 15, kob = (lane >> 4) << 4;
  const int xs2 = (rl & 7) << 3;
  const int ca0 = (kob >> 1) ^ xs2;
  const int ca1 = (32 + (kob >> 1)) ^ xs2;
  const int brow0 = (wc & 1) * 64;
  const unsigned short* ArA = sm + wr * 8192 + rl * 64 + ca0;
  const unsigned short* ArB = sm + wr * 8192 + rl * 64 + ca1;
  const unsigned short* BrA = sm + (2 + (wc >> 1)) * 8192 + (brow0 + rl) * 64 + ca0;
  const unsigned short* BrB = sm + (2 + (wc >> 1)) * 8192 + (brow0 + rl) * 64 + ca1;

  const int srow = tid >> 3;
  const int scol = (((tid & 7) * 16) ^ ((srow & 7) << 4)) >> 1;
  const unsigned short* gA0 = A + (size_t)(m0 + srow) * Kd + scol;
  const unsigned short* gA1 = gA0 + 64 * Kd;
  const unsigned short* gA2 = gA0 + 128 * Kd;
  const unsigned short* gA3 = gA0 + 192 * Kd;
  const unsigned short* gB0 = Bt + (size_t)(n0 + srow) * Kd + scol;
  const unsigned short* gB1 = gB0 + 64 * Kd;
  const unsigned short* gB2 = gB0 + 128 * Kd;
  const unsigned short* gB3 = gB0 + 192 * Kd;
  unsigned short* ldst = sm + tid * 8;

  f32x4 acc[8][4];
#pragma unroll
  for (int i = 0; i < 8; ++i)
#pragma unroll
    for (int j = 0; j < 4; ++j) acc[i][j] = (f32x4){0.f, 0.f, 0.f, 0.f};

#define STG(g0, g1, R, T) do { \
    gll((g0) + (T) * 64, ldst + (R) * 8192); \
    gll((g1) + (T) * 64, ldst + (R) * 8192 + 4096); } while (0)

  STG(gA0, gA1, 0, 0); STG(gA2, gA3, 1, 0);
  STG(gB0, gB1, 2, 0); STG(gB2, gB3, 3, 0);
  STG(gA0, gA1, 4, 1); STG(gA2, gA3, 5, 1);
  S_VMCNT(4);
  BARRIER();

#define KBODY(U, BUF) do { \
    constexpr int BO = (BUF) * 32768; \
    bf16x8 a0[4][2], a1[4][2], b01[2][2], b23[2][2]; \
    _Pragma("unroll") for (int m = 0; m < 4; ++m) { \
      a0[m][0] = *(const bf16x8*)(ArA + BO + m * 1024); \
      a0[m][1] = *(const bf16x8*)(ArB + BO + m * 1024); } \
    _Pragma("unroll") for (int n = 0; n < 2; ++n) { \
      b01[n][0] = *(const bf16x8*)(BrA + BO + n * 1024); \
      b01[n][1] = *(const bf16x8*)(BrB + BO + n * 1024); } \
    if ((U) + 1 < NT) STG(gB0, gB1, (!(BUF)) * 4 + 2, (U) + 1); \
    BARRIER(); \
    __builtin_amdgcn_s_setprio(1); \
    _Pragma("unroll") for (int m = 0; m < 4; ++m) \
      _Pragma("unroll") for (int n = 0; n < 2; ++n) { \
        acc[m][n] = __builtin_amdgcn_mfma_f32_16x16x32_bf16(a0[m][0], b01[n][0], acc[m][n], 0, 0, 0); \
        acc[m][n] = __builtin_amdgcn_mfma_f32_16x16x32_bf16(a0[m][1], b01[n][1], acc[m][n], 0, 0, 0); } \
    __builtin_amdgcn_s_setprio(0); \
    BARRIER(); \
    _Pragma("unroll") for (int m = 0; m < 4; ++m) { \
      a1[m][0] = *(const bf16x8*)(ArA + BO + 4096 + m * 1024); \
      a1[m][1] = *(const bf16x8*)(ArB + BO + 4096 + m * 1024); } \
    if ((U) + 1 < NT) STG(gB2, gB3, (!(BUF)) * 4 + 3, (U) + 1); \
    BARRIER(); \
    __builtin_amdgcn_s_setprio(1); \
    _Pragma("unroll") for (int m = 0; m < 4; ++m) \
      _Pragma("unroll") for (int n = 0; n < 2; ++n) { \
        acc[4 + m][n] = __builtin_amdgcn_mfma_f32_16x16x32_bf16(a1[m][0], b01[n][0], acc[4 + m][n], 0, 0, 0); \
        acc[4 + m][n] = __builtin_amdgcn_mfma_f32_16x16x32_bf16(a1[m][1], b01[n][1], acc[4 + m][n], 0, 0, 0); } \
    __builtin_amdgcn_s_setprio(0); \
    BARRIER(); \
    _Pragma("unroll") for (int n = 0; n < 2; ++n) { \
      b23[n][0] = *(const bf16x8*)(BrA + BO + (2 + n) * 1024); \
      b23[n][1] = *(const bf16x8*)(BrB + BO + (2 + n) * 1024); } \
    if ((U) + 2 < NT) STG(gA0, gA1, (BUF) * 4, (U) + 2); \
    BARRIER(); \
    __builtin_amdgcn_s_setprio(1); \
    _Pragma("unroll") for (int m = 0; m < 4; ++m) \
      _Pragma("unroll") for (int n = 0; n < 2; ++n) { \
        acc[4 + m][2 + n] = __builtin_amdgcn_mfma_f32_16x16x32_bf16(a1[m][0], b23[n][0], acc[4 + m][2 + n], 0, 0, 0); \
        acc[4 + m][2 + n] = __builtin_amdgcn_mfma_f32_16x16x32_bf16(a1[m][1], b23[n][1], acc[4 + m][2 + n], 0, 0, 0); } \
    __builtin_amdgcn_s_setprio(0); \
    BARRIER(); \
    if ((U) + 2 < NT) STG(gA2, gA3, (BUF) * 4 + 1, (U) + 2); \
    BARRIER(); \
    __builtin_amdgcn_s_setprio(1); \
    _Pragma("unroll") for (int m = 0; m < 4; ++m) \
      _Pragma("unroll") for (int n = 0; n < 2; ++n) { \
        acc[m][2 + n] = __builtin_amdgcn_mfma_f32_16x16x32_bf16(a0[m][0], b23[n][0], acc[m][2 + n], 0, 0, 0); \
        acc[m][2 + n] = __builtin_amdgcn_mfma_f32_16x16x32_bf16(a0[m][1], b23[n][1], acc[m][2 + n], 0, 0, 0); } \
    __builtin_amdgcn_s_setprio(0); \
    if ((U) + 2 < NT) { S_VMCNT(4); } else { S_VMCNT(0); } \
    BARRIER(); \
  } while (0)

  for (int u = 0; u < NT; u += 2) {
    KBODY(u, 0);
    KBODY(u + 1, 1);
  }
#undef KBODY
#undef STG

  // ---- epilogue ----
  const int cr = (lane >> 4) * 4, cc = lane & 15;
  float cs[4] = {0.f, 0.f, 0.f, 0.f};
#pragma unroll
  for (int m = 0; m < 8; ++m)
#pragma unroll
    for (int n = 0; n < 4; ++n)
#pragma unroll
      for (int rr = 0; rr < 4; ++rr) {
        const int gr = m0 + wr * 128 + m * 16 + cr + rr;
        const int gc = n0 + wc * 64 + n * 16 + cc;
        float v = acc[m][n][rr];
        if (MODE == 0) {
          const float bias = (gc < 1024) ? b0[gc] : ((gc < 2048) ? b1[gc - 1024] : b2[gc - 2048]);
          v += bias;
          if (gc < 2048) v = 1.f / (1.f + __expf(-v));
          cs[n] += v;
          // head-major plane write: plane=gc>>10, bh=(gr>>12)*16+((gc>>6)&15), l=gr&4095
          const size_t addr = (size_t)(gc >> 10) * PLANE +
                              ((size_t)(((gr >> 12) << 4) | ((gc >> 6) & 15)) * 4096 + (gr & 4095)) * 64 +
                              (gc & 63);
          ((unsigned short*)C)[addr] = f2bf(v);
        } else {
          v += b0[gc];
          ((float*)C)[(size_t)gr * Ndim + gc] = v;
        }
      }
  if (MODE == 0 && n0 < 2048) {
#pragma unroll
    for (int n = 0; n < 4; ++n) {
      cs[n] += __shfl_xor(cs[n], 16);
      cs[n] += __shfl_xor(cs[n], 32);
    }
    if (lane < 16) {
      const int b = m0 >> 12;
#pragma unroll
      for (int n = 0; n < 4; ++n) {
        const int gc = n0 + wc * 64 + n * 16 + lane;
        const int h = (gc & 1023) >> 6, d = gc & 63;
        float* tgt = (gc < 1024) ? qsum_g : ksum_g;
        atomicAdd(&tgt[((b << 4) + h) * 64 + d], cs[n]);
      }
    }
  }
}

// ---------- flow statistics (head-major planes: fully streaming reads) ----------
__global__ __launch_bounds__(256) void flow1_k(const unsigned short* __restrict__ Qp,
                                               const unsigned short* __restrict__ Kp,
                                               const float* __restrict__ ksum, const float* __restrict__ qsum,
                                               float* __restrict__ si, float* __restrict__ qsi,
                                               float* __restrict__ kso) {
  const int bh = blockIdx.x >> 3, c = blockIdx.x & 7;
  const int w = threadIdx.x >> 6, lane = threadIdx.x & 63;
  const float ks = ksum[bh * 64 + lane] + FEPS;
  const float qs = qsum[bh * 64 + lane] + FEPS;
  const size_t hb = (size_t)bh * 262144 + lane;
  float qsi_acc = 0.f, kso_acc = 0.f;
  const int l0 = c * 512 + w * 128;
  for (int l = l0; l < l0 + 128; l += 4) {
    float qv[4], kvv[4], dq[4], dk[4];
#pragma unroll
    for (int u = 0; u < 4; ++u) {
      const size_t off = hb + (size_t)(l + u) * 64;
      qv[u] = bf2f(Qp[off]);
      kvv[u] = bf2f(Kp[off]);
      dq[u] = (qv[u] + FEPS) * ks;
      dk[u] = (kvv[u] + FEPS) * qs;
    }
#pragma unroll
    for (int m = 1; m < 64; m <<= 1)
#pragma unroll
      for (int u = 0; u < 4; ++u) { dq[u] += __shfl_xor(dq[u], m); dk[u] += __shfl_xor(dk[u], m); }
#pragma unroll
    for (int u = 0; u < 4; ++u) {
      const float siv = 1.f / dq[u], sov = 1.f / dk[u];
      if (lane == 0) si[(size_t)bh * SEQ + l + u] = siv;
      qsi_acc += qv[u] * siv;
      kso_acc += kvv[u] * sov;
    }
  }
  atomicAdd(&qsi[bh * 64 + lane], qsi_acc);
  atomicAdd(&kso[bh * 64 + lane], kso_acc);
}

// fused: sink_allocation + ee (LDS) + esum, then kv partial for the same 512 rows
__global__ __launch_bounds__(256) void flow2kv_k(const unsigned short* __restrict__ Qp,
                                                 const unsigned short* __restrict__ Kp,
                                                 const unsigned short* __restrict__ Vp,
                                                 const float* __restrict__ qsi, const float* __restrict__ kso,
                                                 float* __restrict__ sa, float* __restrict__ esum,
                                                 float* __restrict__ kvp) {
  const int bh = blockIdx.x >> 3, c = blockIdx.x & 7;
  __shared__ float eel[512];
  __shared__ float kch[32][64];
  __shared__ float vch[32][64];
  const int t = threadIdx.x;
  const int w = t >> 6, lane = t & 63;
  const size_t hb = (size_t)bh * 262144;

  {
    const float kov = kso[bh * 64 + lane] + FEPS;
    const float qiv = qsi[bh * 64 + lane] + FEPS;
    const size_t base = hb + lane;
    float es = 0.f;
    const int l0 = c * 512 + w * 128;
    for (int l = l0; l < l0 + 128; l += 4) {
      float ds[4], dr[4];
#pragma unroll
      for (int u = 0; u < 4; ++u) {
        const size_t off = base + (size_t)(l + u) * 64;
        ds[u] = (bf2f(Qp[off]) + FEPS) * kov;
        dr[u] = (bf2f(Kp[off]) + FEPS) * qiv;
      }
#pragma unroll
      for (int m = 1; m < 64; m <<= 1)
#pragma unroll
        for (int u = 0; u < 4; ++u) { ds[u] += __shfl_xor(ds[u], m); dr[u] += __shfl_xor(dr[u], m); }
#pragma unroll
      for (int u = 0; u < 4; ++u) {
        const float sig = 1.f / (1.f + __expf(-ds[u]));
        const float cse = fminf(1.f, fmaxf(-1.f, dr[u]));
        const float e = __expf(cse);
        if (lane == 0) { sa[(size_t)bh * SEQ + l + u] = sig; eel[l - c * 512 + u] = e; }
        es += e;
      }
    }
    if (lane == 0) atomicAdd(&esum[bh], es);
  }
  __syncthreads();

  const int sl = t >> 3, sd = (t & 7) * 8;
  const int d1 = (t >> 4) * 4, d2 = (t & 15) * 4;
  float acc[4][4] = {};
  for (int ch = 0; ch < 16; ++ch) {
    const int lloc = ch * 32 + sl;
    const size_t off = hb + (size_t)(c * 512 + lloc) * 64 + sd;
    const uint4 kr = *(const uint4*)(Kp + off);
    const uint4 vr = *(const uint4*)(Vp + off);
    const float cmp = eel[lloc];
    float kd[8], vd[8];
    decode8(kr, kd); decode8(vr, vd);
    __syncthreads();
    *(f32x4*)&kch[sl][sd]     = (f32x4){kd[0], kd[1], kd[2], kd[3]};
    *(f32x4*)&kch[sl][sd + 4] = (f32x4){kd[4], kd[5], kd[6], kd[7]};
    *(f32x4*)&vch[sl][sd]     = (f32x4){vd[0] * cmp, vd[1] * cmp, vd[2] * cmp, vd[3] * cmp};
    *(f32x4*)&vch[sl][sd + 4] = (f32x4){vd[4] * cmp, vd[5] * cmp, vd[6] * cmp, vd[7] * cmp};
    __syncthreads();
    for (int l = 0; l < 32; ++l) {
      const f32x4 ka = *(const f32x4*)&kch[l][d1];
      const f32x4 vb = *(const f32x4*)&vch[l][d2];
#pragma unroll
      for (int i = 0; i < 4; ++i)
#pragma unroll
        for (int j = 0; j < 4; ++j) acc[i][j] += ka[i] * vb[j];
    }
    __syncthreads();
  }
  float* dst = kvp + (size_t)blockIdx.x * 4096;
#pragma unroll
  for (int i = 0; i < 4; ++i)
    *(f32x4*)&dst[(d1 + i) * 64 + d2] = (f32x4){acc[i][0], acc[i][1], acc[i][2], acc[i][3]};
}

__global__ __launch_bounds__(256) void kvred_k(const float* __restrict__ kvp,
                                               const float* __restrict__ esum,
                                               float* __restrict__ kvf) {
  const int idx = blockIdx.x * 256 + threadIdx.x;
  const int bh = idx >> 12, e = idx & 4095;
  const float Ls = 4096.f / esum[bh];
  float s = 0.f;
#pragma unroll
  for (int cN = 0; cN < 8; ++cN) s += kvp[((size_t)(bh * 8 + cN) << 12) + e];
  kvf[idx] = s * Ls;
}

// out = (q*si)@kv * sa -> bf16 AOb token-major head-merged. grid NBH*16.
__global__ __launch_bounds__(256) void outk_k(const unsigned short* __restrict__ Qp,
                                              const float* __restrict__ kvf, const float* __restrict__ si,
                                              const float* __restrict__ sa,
                                              unsigned short* __restrict__ AOb) {
  const int bh = blockIdx.x >> 4, lc = blockIdx.x & 15;
  const int b = bh >> 4, h = bh & 15;
  __shared__ float kvs[4096];
  __shared__ float qs_[64 * 128];
  const int t = threadIdx.x;
  for (int i = t; i < 1024; i += 256)
    *(f32x4*)&kvs[i * 4] = *(const f32x4*)&kvf[(size_t)bh * 4096 + i * 4];
  const size_t hb = (size_t)bh * 262144;
  const int lb = (t >> 4) * 8, d2 = (t & 15) * 4;
  const int sl = t & 127, sd0 = (t >> 7) * 8;
  for (int sub = 0; sub < 2; ++sub) {
    const int l0 = lc * 256 + sub * 128;
    __syncthreads();
#pragma unroll
    for (int p = 0; p < 4; ++p) {
      const int d0 = sd0 + p * 16;
      const uint4 raw = *(const uint4*)(Qp + hb + (size_t)(l0 + sl) * 64 + d0);
      float qd[8]; decode8(raw, qd);
#pragma unroll
      for (int i = 0; i < 8; ++i) qs_[(d0 + i) * 128 + sl] = qd[i];
    }
    __syncthreads();
    float acc[8][4] = {};
    for (int dd = 0; dd < 64; ++dd) {
      const f32x4 kvv = *(const f32x4*)&kvs[dd * 64 + d2];
      const f32x4 qa = *(const f32x4*)&qs_[dd * 128 + lb];
      const f32x4 qb = *(const f32x4*)&qs_[dd * 128 + lb + 4];
#pragma unroll
      for (int i = 0; i < 4; ++i)
#pragma unroll
        for (int j = 0; j < 4; ++j) { acc[i][j] += qa[i] * kvv[j]; acc[i + 4][j] += qb[i] * kvv[j]; }
    }
#pragma unroll
    for (int i = 0; i < 8; ++i) {
      const int l = l0 + lb + i;
      const size_t sidx = (size_t)bh * SEQ + l;
      const float sc = si[sidx] * sa[sidx];
      ushort4 o;
      o.x = f2bf(acc[i][0] * sc); o.y = f2bf(acc[i][1] * sc);
      o.z = f2bf(acc[i][2] * sc); o.w = f2bf(acc[i][3] * sc);
      *(ushort4*)(AOb + (size_t)(b * SEQ + l) * 1024 + h * 64 + d2) = o;
    }
  }
}

extern "C" void kernel_launch(void* const* d_in, const int* in_sizes, int n_in,
                              void* d_out, int out_size, void* d_ws, size_t ws_size,
                              hipStream_t stream) {
  const float* x  = (const float*)d_in[0];
  const float* Wq = (const float*)d_in[1];
  const float* bq = (const float*)d_in[2];
  const float* Wk = (const float*)d_in[3];
  const float* bk = (const float*)d_in[4];
  const float* Wv = (const float*)d_in[5];
  const float* bv = (const float*)d_in[6];
  const float* Wo = (const float*)d_in[7];
  const float* bo = (const float*)d_in[8];
  char* ws = (char*)d_ws;
  unsigned short* Xb    = (unsigned short*)(ws + XB_OFF);
  unsigned short* Wqkvt = (unsigned short*)(ws + WQKV_OFF);
  unsigned short* Wot   = (unsigned short*)(ws + WO_OFF);
  unsigned short* QKV   = (unsigned short*)(ws + QKV_OFF);
  unsigned short* AOb   = (unsigned short*)(ws + AOB_OFF);
  unsigned short* Qp = QKV;
  unsigned short* Kp = QKV + PLANE;
  unsigned short* Vp = QKV + 2 * PLANE;
  float* ksum = (float*)(ws + KSUM_OFF);
  float* qsum = (float*)(ws + QSUM_OFF);
  float* qsi  = (float*)(ws + QSI_OFF);
  float* kso  = (float*)(ws + KSO_OFF);
  float* esum = (float*)(ws + ESUM_OFF);
  float* si   = (float*)(ws + SI_OFF);
  float* sa   = (float*)(ws + SA_OFF);
  float* kvf  = (float*)(ws + KVF_OFF);
  float* kvp  = (float*)(ws + KVP_OFF);

  (void)hipMemsetAsync(ws + ST_OFF, 0, 81920, stream);  // zero small atomic accumulators
  conv_all_k<<<3072, 256, 0, stream>>>(x, Wq, Wk, Wv, Wo, Xb, Wqkvt, Wot);
  gemm8p<0><<<dim3(12, 64), 512, 0, stream>>>(Xb, Wqkvt, bq, bk, bv, qsum, ksum, (void*)QKV, 3072);
  flow1_k<<<NBH * 8, 256, 0, stream>>>(Qp, Kp, ksum, qsum, si, qsi, kso);
  flow2kv_k<<<NBH * 8, 256, 0, stream>>>(Qp, Kp, Vp, qsi, kso, sa, esum, kvp);
  kvred_k<<<1024, 256, 0, stream>>>(kvp, esum, kvf);
  outk_k<<<NBH * 16, 256, 0, stream>>>(Qp, kvf, si, sa, AOb);
  gemm8p<1><<<dim3(4, 64), 512, 0, stream>>>(AOb, Wot, bo, nullptr, nullptr, nullptr, nullptr, d_out, 1024);
}

// Round 19
// 335.254 us; speedup vs baseline: 1.1029x; 1.0420x over previous
//
#include <hip/hip_runtime.h>
#include <hip/hip_bf16.h>
#include <stdint.h>

#define SEQ    4096
#define DMODEL 1024
#define NHEAD  16
#define HDIM   64
#define NBATCH 4
#define NBH    (NBATCH*NHEAD)     // 64
#define MTOK   (NBATCH*SEQ)       // 16384
#define FEPS   1e-6f
#define PLANE  16777216u          // 16384*1024 shorts per Q/K/V plane

typedef float f32x4 __attribute__((ext_vector_type(4)));
typedef short bf16x8 __attribute__((ext_vector_type(8)));

// ---------- workspace layout (bytes) ----------
#define XB_OFF    0u                      // 16384*1024 bf16 = 33554432
#define WQKV_OFF  33554432u               // 3072*1024 bf16  = 6291456
#define WO_OFF    39845888u               // 1024*1024 bf16  = 2097152
#define QKV_OFF   41943040u               // 3 planes x 32MB = 100663296
#define AOB_OFF   142606336u              // 16384*1024 bf16 = 33554432
#define ST_OFF    176160768u
#define KSUM_OFF  (ST_OFF)                // 4096 f32
#define QSUM_OFF  (ST_OFF + 16384u)
#define QSI_OFF   (ST_OFF + 32768u)
#define KSO_OFF   (ST_OFF + 49152u)
#define ESUM_OFF  (ST_OFF + 65536u)       // 64 f32 (padded)
#define SI_OFF    (ST_OFF + 81920u)       // 262144 f32 = 1 MB
#define SA_OFF    (SI_OFF + 1048576u)
#define KVF_OFF   (SA_OFF + 1048576u)     // 64*64*64 f32 = 1 MB
#define KVP_OFF   (KVF_OFF + 1048576u)    // 8 MB partials

#define S_VMCNT(N) asm volatile("s_waitcnt vmcnt(" #N ")" ::: "memory")
#define BARRIER() do { __builtin_amdgcn_s_barrier(); asm volatile("" ::: "memory"); } while (0)

__device__ __forceinline__ unsigned short f2bf(float f) {
  __hip_bfloat16 h = __float2bfloat16(f);
  unsigned short u; __builtin_memcpy(&u, &h, 2); return u;
}
__device__ __forceinline__ float bf2f(unsigned short u) {
  union { unsigned u; float f; } x; x.u = ((unsigned)u) << 16; return x.f;
}
__device__ __forceinline__ void decode8(uint4 r, float* o) {
  o[0] = bf2f((unsigned short)(r.x & 0xffffu)); o[1] = bf2f((unsigned short)(r.x >> 16));
  o[2] = bf2f((unsigned short)(r.y & 0xffffu)); o[3] = bf2f((unsigned short)(r.y >> 16));
  o[4] = bf2f((unsigned short)(r.z & 0xffffu)); o[5] = bf2f((unsigned short)(r.z >> 16));
  o[6] = bf2f((unsigned short)(r.w & 0xffffu)); o[7] = bf2f((unsigned short)(r.w >> 16));
}
__device__ __forceinline__ void gll(const unsigned short* g, unsigned short* l) {
  __builtin_amdgcn_global_load_lds((const __attribute__((address_space(1))) void*)g,
      (__attribute__((address_space(3))) void*)l, 16, 0, 0);
}

// ---------- fused conversions: blocks 0-1023 = W transpose, 1024+ = x convert ----------
__global__ __launch_bounds__(256) void conv_all_k(const float* __restrict__ x,
                                                  const float* __restrict__ Wq, const float* __restrict__ Wk,
                                                  const float* __restrict__ Wv, const float* __restrict__ Wo,
                                                  unsigned short* __restrict__ xb,
                                                  unsigned short* __restrict__ Wqkvt,
                                                  unsigned short* __restrict__ Wot) {
  const int bx = blockIdx.x;
  if (bx < 1024) {
    __shared__ float tile[64][65];
    const int z = bx >> 8, tl = bx & 255;
    const float* W = (z == 0) ? Wq : (z == 1) ? Wk : (z == 2) ? Wv : Wo;
    unsigned short* dst = (z < 3) ? (Wqkvt + (size_t)z * 1024u * 1024u) : Wot;
    const int n0 = (tl & 15) * 64, k0 = (tl >> 4) * 64;
    const int tx = threadIdx.x & 63, ty = threadIdx.x >> 6;
    for (int i = ty; i < 64; i += 4)
      tile[i][tx] = W[(size_t)(k0 + i) * 1024 + n0 + tx];
    __syncthreads();
    for (int i = ty; i < 64; i += 4)
      dst[(size_t)(n0 + i) * 1024 + k0 + tx] = f2bf(tile[tx][i]);
  } else {
    const int n = MTOK * DMODEL;
    int i = ((bx - 1024) * 256 + threadIdx.x) * 4;
    const int stride = (gridDim.x - 1024) * 256 * 4;
    for (; i < n; i += stride) {
      float4 v = *(const float4*)(x + i);
      ushort4 o;
      o.x = f2bf(v.x); o.y = f2bf(v.y); o.z = f2bf(v.z); o.w = f2bf(v.w);
      *(ushort4*)(xb + i) = o;
    }
  }
}

// ---------- 256x256 GEMM, K=1024, BK=64, 4-phase/K-tile, single counted vmcnt ----------
// MODE 0: N=3072, bias+sigmoid epilogue, writes Q/K/V head-major planes
//         [bh][l][64] bf16 (plane = gc>>10), fused q/k per-column sums.
// MODE 1: N=1024, bias b0, fp32 row-major out.
template <int MODE>
__global__ __launch_bounds__(512, 2) void gemm8p(const unsigned short* __restrict__ A,
                                                 const unsigned short* __restrict__ Bt,
                                                 const float* __restrict__ b0,
                                                 const float* __restrict__ b1,
                                                 const float* __restrict__ b2,
                                                 float* __restrict__ qsum_g,
                                                 float* __restrict__ ksum_g,
                                                 void* __restrict__ C, int Ndim) {
  constexpr int Kd = 1024;
  constexpr int NT = Kd >> 6;
  __shared__ unsigned short sm[8 * 8192];                // 128 KiB
  const int tid = threadIdx.x;
  const int wid = tid >> 6, lane = tid & 63;
  const int wr = wid >> 2, wc = wid & 3;

  const int gx = gridDim.x;
  const int nwg = gx * gridDim.y;
  int wg = blockIdx.y * gx + blockIdx.x;
  wg = (wg & 7) * (nwg >> 3) + (wg >> 3);
  const int n0 = (wg % gx) * 256, m0 = (wg / gx) * 256;

  const int rl = lane & 15, kob = (lane >> 4) << 4;
  const int xs2 = (rl & 7) << 3;
  const int ca0 = (kob >> 1) ^ xs2;
  const int ca1 = (32 + (kob >> 1)) ^ xs2;
  const int brow0 = (wc & 1) * 64;
  const unsigned short* ArA = sm + wr * 8192 + rl * 64 + ca0;
  const unsigned short* ArB = sm + wr * 8192 + rl * 64 + ca1;
  const unsigned short* BrA = sm + (2 + (wc >> 1)) * 8192 + (brow0 + rl) * 64 + ca0;
  const unsigned short* BrB = sm + (2 + (wc >> 1)) * 8192 + (brow0 + rl) * 64 + ca1;

  const int srow = tid >> 3;
  const int scol = (((tid & 7) * 16) ^ ((srow & 7) << 4)) >> 1;
  const unsigned short* gA0 = A + (size_t)(m0 + srow) * Kd + scol;
  const unsigned short* gA1 = gA0 + 64 * Kd;
  const unsigned short* gA2 = gA0 + 128 * Kd;
  const unsigned short* gA3 = gA0 + 192 * Kd;
  const unsigned short* gB0 = Bt + (size_t)(n0 + srow) * Kd + scol;
  const unsigned short* gB1 = gB0 + 64 * Kd;
  const unsigned short* gB2 = gB0 + 128 * Kd;
  const unsigned short* gB3 = gB0 + 192 * Kd;
  unsigned short* ldst = sm + tid * 8;

  f32x4 acc[8][4];
#pragma unroll
  for (int i = 0; i < 8; ++i)
#pragma unroll
    for (int j = 0; j < 4; ++j) acc[i][j] = (f32x4){0.f, 0.f, 0.f, 0.f};

#define STG(g0, g1, R, T) do { \
    gll((g0) + (T) * 64, ldst + (R) * 8192); \
    gll((g1) + (T) * 64, ldst + (R) * 8192 + 4096); } while (0)

  STG(gA0, gA1, 0, 0); STG(gA2, gA3, 1, 0);
  STG(gB0, gB1, 2, 0); STG(gB2, gB3, 3, 0);
  STG(gA0, gA1, 4, 1); STG(gA2, gA3, 5, 1);
  S_VMCNT(4);
  BARRIER();

#define KBODY(U, BUF) do { \
    constexpr int BO = (BUF) * 32768; \
    bf16x8 a0[4][2], a1[4][2], b01[2][2], b23[2][2]; \
    _Pragma("unroll") for (int m = 0; m < 4; ++m) { \
      a0[m][0] = *(const bf16x8*)(ArA + BO + m * 1024); \
      a0[m][1] = *(const bf16x8*)(ArB + BO + m * 1024); } \
    _Pragma("unroll") for (int n = 0; n < 2; ++n) { \
      b01[n][0] = *(const bf16x8*)(BrA + BO + n * 1024); \
      b01[n][1] = *(const bf16x8*)(BrB + BO + n * 1024); } \
    if ((U) + 1 < NT) STG(gB0, gB1, (!(BUF)) * 4 + 2, (U) + 1); \
    BARRIER(); \
    __builtin_amdgcn_s_setprio(1); \
    _Pragma("unroll") for (int m = 0; m < 4; ++m) \
      _Pragma("unroll") for (int n = 0; n < 2; ++n) { \
        acc[m][n] = __builtin_amdgcn_mfma_f32_16x16x32_bf16(a0[m][0], b01[n][0], acc[m][n], 0, 0, 0); \
        acc[m][n] = __builtin_amdgcn_mfma_f32_16x16x32_bf16(a0[m][1], b01[n][1], acc[m][n], 0, 0, 0); } \
    __builtin_amdgcn_s_setprio(0); \
    BARRIER(); \
    _Pragma("unroll") for (int m = 0; m < 4; ++m) { \
      a1[m][0] = *(const bf16x8*)(ArA + BO + 4096 + m * 1024); \
      a1[m][1] = *(const bf16x8*)(ArB + BO + 4096 + m * 1024); } \
    if ((U) + 1 < NT) STG(gB2, gB3, (!(BUF)) * 4 + 3, (U) + 1); \
    BARRIER(); \
    __builtin_amdgcn_s_setprio(1); \
    _Pragma("unroll") for (int m = 0; m < 4; ++m) \
      _Pragma("unroll") for (int n = 0; n < 2; ++n) { \
        acc[4 + m][n] = __builtin_amdgcn_mfma_f32_16x16x32_bf16(a1[m][0], b01[n][0], acc[4 + m][n], 0, 0, 0); \
        acc[4 + m][n] = __builtin_amdgcn_mfma_f32_16x16x32_bf16(a1[m][1], b01[n][1], acc[4 + m][n], 0, 0, 0); } \
    __builtin_amdgcn_s_setprio(0); \
    BARRIER(); \
    _Pragma("unroll") for (int n = 0; n < 2; ++n) { \
      b23[n][0] = *(const bf16x8*)(BrA + BO + (2 + n) * 1024); \
      b23[n][1] = *(const bf16x8*)(BrB + BO + (2 + n) * 1024); } \
    if ((U) + 2 < NT) STG(gA0, gA1, (BUF) * 4, (U) + 2); \
    BARRIER(); \
    __builtin_amdgcn_s_setprio(1); \
    _Pragma("unroll") for (int m = 0; m < 4; ++m) \
      _Pragma("unroll") for (int n = 0; n < 2; ++n) { \
        acc[4 + m][2 + n] = __builtin_amdgcn_mfma_f32_16x16x32_bf16(a1[m][0], b23[n][0], acc[4 + m][2 + n], 0, 0, 0); \
        acc[4 + m][2 + n] = __builtin_amdgcn_mfma_f32_16x16x32_bf16(a1[m][1], b23[n][1], acc[4 + m][2 + n], 0, 0, 0); } \
    __builtin_amdgcn_s_setprio(0); \
    BARRIER(); \
    if ((U) + 2 < NT) STG(gA2, gA3, (BUF) * 4 + 1, (U) + 2); \
    BARRIER(); \
    __builtin_amdgcn_s_setprio(1); \
    _Pragma("unroll") for (int m = 0; m < 4; ++m) \
      _Pragma("unroll") for (int n = 0; n < 2; ++n) { \
        acc[m][2 + n] = __builtin_amdgcn_mfma_f32_16x16x32_bf16(a0[m][0], b23[n][0], acc[m][2 + n], 0, 0, 0); \
        acc[m][2 + n] = __builtin_amdgcn_mfma_f32_16x16x32_bf16(a0[m][1], b23[n][1], acc[m][2 + n], 0, 0, 0); } \
    __builtin_amdgcn_s_setprio(0); \
    if ((U) + 2 < NT) { S_VMCNT(4); } else { S_VMCNT(0); } \
    BARRIER(); \
  } while (0)

  for (int u = 0; u < NT; u += 2) {
    KBODY(u, 0);
    KBODY(u + 1, 1);
  }
#undef KBODY
#undef STG

  // ---- epilogue ----
  const int cr = (lane >> 4) * 4, cc = lane & 15;
  float cs[4] = {0.f, 0.f, 0.f, 0.f};
#pragma unroll
  for (int m = 0; m < 8; ++m)
#pragma unroll
    for (int n = 0; n < 4; ++n)
#pragma unroll
      for (int rr = 0; rr < 4; ++rr) {
        const int gr = m0 + wr * 128 + m * 16 + cr + rr;
        const int gc = n0 + wc * 64 + n * 16 + cc;
        float v = acc[m][n][rr];
        if (MODE == 0) {
          const float bias = (gc < 1024) ? b0[gc] : ((gc < 2048) ? b1[gc - 1024] : b2[gc - 2048]);
          v += bias;
          if (gc < 2048) v = 1.f / (1.f + __expf(-v));
          cs[n] += v;
          // head-major plane write: plane=gc>>10, bh=(gr>>12)*16+((gc>>6)&15), l=gr&4095
          const size_t addr = (size_t)(gc >> 10) * PLANE +
                              ((size_t)(((gr >> 12) << 4) | ((gc >> 6) & 15)) * 4096 + (gr & 4095)) * 64 +
                              (gc & 63);
          ((unsigned short*)C)[addr] = f2bf(v);
        } else {
          v += b0[gc];
          ((float*)C)[(size_t)gr * Ndim + gc] = v;
        }
      }
  if (MODE == 0 && n0 < 2048) {
#pragma unroll
    for (int n = 0; n < 4; ++n) {
      cs[n] += __shfl_xor(cs[n], 16);
      cs[n] += __shfl_xor(cs[n], 32);
    }
    if (lane < 16) {
      const int b = m0 >> 12;
#pragma unroll
      for (int n = 0; n < 4; ++n) {
        const int gc = n0 + wc * 64 + n * 16 + lane;
        const int h = (gc & 1023) >> 6, d = gc & 63;
        float* tgt = (gc < 1024) ? qsum_g : ksum_g;
        atomicAdd(&tgt[((b << 4) + h) * 64 + d], cs[n]);
      }
    }
  }
}

// ---------- flow statistics (head-major planes: fully streaming reads) ----------
__global__ __launch_bounds__(256) void flow1_k(const unsigned short* __restrict__ Qp,
                                               const unsigned short* __restrict__ Kp,
                                               const float* __restrict__ ksum, const float* __restrict__ qsum,
                                               float* __restrict__ si, float* __restrict__ qsi,
                                               float* __restrict__ kso) {
  const int bh = blockIdx.x >> 3, c = blockIdx.x & 7;
  const int w = threadIdx.x >> 6, lane = threadIdx.x & 63;
  const float ks = ksum[bh * 64 + lane] + FEPS;
  const float qs = qsum[bh * 64 + lane] + FEPS;
  const size_t hb = (size_t)bh * 262144 + lane;
  float qsi_acc = 0.f, kso_acc = 0.f;
  const int l0 = c * 512 + w * 128;
  for (int l = l0; l < l0 + 128; l += 4) {
    float qv[4], kvv[4], dq[4], dk[4];
#pragma unroll
    for (int u = 0; u < 4; ++u) {
      const size_t off = hb + (size_t)(l + u) * 64;
      qv[u] = bf2f(Qp[off]);
      kvv[u] = bf2f(Kp[off]);
      dq[u] = (qv[u] + FEPS) * ks;
      dk[u] = (kvv[u] + FEPS) * qs;
    }
#pragma unroll
    for (int m = 1; m < 64; m <<= 1)
#pragma unroll
      for (int u = 0; u < 4; ++u) { dq[u] += __shfl_xor(dq[u], m); dk[u] += __shfl_xor(dk[u], m); }
#pragma unroll
    for (int u = 0; u < 4; ++u) {
      const float siv = 1.f / dq[u], sov = 1.f / dk[u];
      if (lane == 0) si[(size_t)bh * SEQ + l + u] = siv;
      qsi_acc += qv[u] * siv;
      kso_acc += kvv[u] * sov;
    }
  }
  atomicAdd(&qsi[bh * 64 + lane], qsi_acc);
  atomicAdd(&kso[bh * 64 + lane], kso_acc);
}

// fused: sink_allocation + ee (LDS) + esum, then kv partial for the same 512 rows
__global__ __launch_bounds__(256) void flow2kv_k(const unsigned short* __restrict__ Qp,
                                                 const unsigned short* __restrict__ Kp,
                                                 const unsigned short* __restrict__ Vp,
                                                 const float* __restrict__ qsi, const float* __restrict__ kso,
                                                 float* __restrict__ sa, float* __restrict__ esum,
                                                 float* __restrict__ kvp) {
  const int bh = blockIdx.x >> 3, c = blockIdx.x & 7;
  __shared__ float eel[512];
  __shared__ float kch[32][64];
  __shared__ float vch[32][64];
  const int t = threadIdx.x;
  const int w = t >> 6, lane = t & 63;
  const size_t hb = (size_t)bh * 262144;

  {
    const float kov = kso[bh * 64 + lane] + FEPS;
    const float qiv = qsi[bh * 64 + lane] + FEPS;
    const size_t base = hb + lane;
    float es = 0.f;
    const int l0 = c * 512 + w * 128;
    for (int l = l0; l < l0 + 128; l += 4) {
      float ds[4], dr[4];
#pragma unroll
      for (int u = 0; u < 4; ++u) {
        const size_t off = base + (size_t)(l + u) * 64;
        ds[u] = (bf2f(Qp[off]) + FEPS) * kov;
        dr[u] = (bf2f(Kp[off]) + FEPS) * qiv;
      }
#pragma unroll
      for (int m = 1; m < 64; m <<= 1)
#pragma unroll
        for (int u = 0; u < 4; ++u) { ds[u] += __shfl_xor(ds[u], m); dr[u] += __shfl_xor(dr[u], m); }
#pragma unroll
      for (int u = 0; u < 4; ++u) {
        const float sig = 1.f / (1.f + __expf(-ds[u]));
        const float cse = fminf(1.f, fmaxf(-1.f, dr[u]));
        const float e = __expf(cse);
        if (lane == 0) { sa[(size_t)bh * SEQ + l + u] = sig; eel[l - c * 512 + u] = e; }
        es += e;
      }
    }
    if (lane == 0) atomicAdd(&esum[bh], es);
  }
  __syncthreads();

  const int sl = t >> 3, sd = (t & 7) * 8;
  const int d1 = (t >> 4) * 4, d2 = (t & 15) * 4;
  float acc[4][4] = {};
  for (int ch = 0; ch < 16; ++ch) {
    const int lloc = ch * 32 + sl;
    const size_t off = hb + (size_t)(c * 512 + lloc) * 64 + sd;
    const uint4 kr = *(const uint4*)(Kp + off);
    const uint4 vr = *(const uint4*)(Vp + off);
    const float cmp = eel[lloc];
    float kd[8], vd[8];
    decode8(kr, kd); decode8(vr, vd);
    __syncthreads();
    *(f32x4*)&kch[sl][sd]     = (f32x4){kd[0], kd[1], kd[2], kd[3]};
    *(f32x4*)&kch[sl][sd + 4] = (f32x4){kd[4], kd[5], kd[6], kd[7]};
    *(f32x4*)&vch[sl][sd]     = (f32x4){vd[0] * cmp, vd[1] * cmp, vd[2] * cmp, vd[3] * cmp};
    *(f32x4*)&vch[sl][sd + 4] = (f32x4){vd[4] * cmp, vd[5] * cmp, vd[6] * cmp, vd[7] * cmp};
    __syncthreads();
    for (int l = 0; l < 32; ++l) {
      const f32x4 ka = *(const f32x4*)&kch[l][d1];
      const f32x4 vb = *(const f32x4*)&vch[l][d2];
#pragma unroll
      for (int i = 0; i < 4; ++i)
#pragma unroll
        for (int j = 0; j < 4; ++j) acc[i][j] += ka[i] * vb[j];
    }
    __syncthreads();
  }
  float* dst = kvp + (size_t)blockIdx.x * 4096;
#pragma unroll
  for (int i = 0; i < 4; ++i)
    *(f32x4*)&dst[(d1 + i) * 64 + d2] = (f32x4){acc[i][0], acc[i][1], acc[i][2], acc[i][3]};
}

__global__ __launch_bounds__(256) void kvred_k(const float* __restrict__ kvp,
                                               const float* __restrict__ esum,
                                               float* __restrict__ kvf) {
  const int idx = blockIdx.x * 256 + threadIdx.x;
  const int bh = idx >> 12, e = idx & 4095;
  const float Ls = 4096.f / esum[bh];
  float s = 0.f;
#pragma unroll
  for (int cN = 0; cN < 8; ++cN) s += kvp[((size_t)(bh * 8 + cN) << 12) + e];
  kvf[idx] = s * Ls;
}

// out = (Q @ kv) row-scaled by si*sa -> bf16 AOb token-major. MFMA version.
// grid NBH*16, 256 thr = 4 waves; per block 256 rows; kvT bf16 in LDS (swizzled).
__global__ __launch_bounds__(256) void outk_k(const unsigned short* __restrict__ Qp,
                                              const float* __restrict__ kvf, const float* __restrict__ si,
                                              const float* __restrict__ sa,
                                              unsigned short* __restrict__ AOb) {
  const int bh = blockIdx.x >> 4, lc = blockIdx.x & 15;
  const int b = bh >> 4, h = bh & 15;
  __shared__ unsigned short kvT[4096];                   // [d][dd] bf16, 8-blk XOR swizzle
  const int t = threadIdx.x;
  const int w = t >> 6, lane = t & 63;
  // transpose + convert kvf [dd][d] -> kvT[d][dd^((d&7)<<3)]
  for (int i = t; i < 4096; i += 256) {
    const int dd = i >> 6, d = i & 63;
    kvT[d * 64 + (dd ^ ((d & 7) << 3))] = f2bf(kvf[(size_t)bh * 4096 + i]);
  }
  __syncthreads();

  const int rl = lane & 15, g = lane >> 4;               // g = 0..3 (k-group)
  const size_t hb = (size_t)bh * 262144;
  const int l0 = lc * 256 + w * 64;

  bf16x8 a[4][2], bf[4][2];
#pragma unroll
  for (int m = 0; m < 4; ++m) {
    const size_t q0 = hb + (size_t)(l0 + m * 16 + rl) * 64 + g * 8;
    a[m][0] = *(const bf16x8*)(Qp + q0);
    a[m][1] = *(const bf16x8*)(Qp + q0 + 32);
  }
#pragma unroll
  for (int n = 0; n < 4; ++n) {
    const int r = n * 16 + rl;
    const int sw = (r & 7) << 3;
    bf[n][0] = *(const bf16x8*)(kvT + r * 64 + ((g * 8) ^ sw));
    bf[n][1] = *(const bf16x8*)(kvT + r * 64 + ((32 + g * 8) ^ sw));
  }
  f32x4 acc[4][4];
#pragma unroll
  for (int i = 0; i < 4; ++i)
#pragma unroll
    for (int j = 0; j < 4; ++j) acc[i][j] = (f32x4){0.f, 0.f, 0.f, 0.f};
#pragma unroll
  for (int m = 0; m < 4; ++m)
#pragma unroll
    for (int n = 0; n < 4; ++n) {
      acc[m][n] = __builtin_amdgcn_mfma_f32_16x16x32_bf16(a[m][0], bf[n][0], acc[m][n], 0, 0, 0);
      acc[m][n] = __builtin_amdgcn_mfma_f32_16x16x32_bf16(a[m][1], bf[n][1], acc[m][n], 0, 0, 0);
    }

  // epilogue: row-scale by si*sa, write token-major AOb
  const int cr = (lane >> 4) * 4, cc = lane & 15;
#pragma unroll
  for (int m = 0; m < 4; ++m)
#pragma unroll
    for (int rr = 0; rr < 4; ++rr) {
      const int l = l0 + m * 16 + cr + rr;
      const size_t sidx = (size_t)bh * SEQ + l;
      const float sc = si[sidx] * sa[sidx];
      unsigned short* orow = AOb + (size_t)(b * SEQ + l) * 1024 + h * 64 + cc;
#pragma unroll
      for (int n = 0; n < 4; ++n)
        orow[n * 16] = f2bf(acc[m][n][rr] * sc);
    }
}

extern "C" void kernel_launch(void* const* d_in, const int* in_sizes, int n_in,
                              void* d_out, int out_size, void* d_ws, size_t ws_size,
                              hipStream_t stream) {
  const float* x  = (const float*)d_in[0];
  const float* Wq = (const float*)d_in[1];
  const float* bq = (const float*)d_in[2];
  const float* Wk = (const float*)d_in[3];
  const float* bk = (const float*)d_in[4];
  const float* Wv = (const float*)d_in[5];
  const float* bv = (const float*)d_in[6];
  const float* Wo = (const float*)d_in[7];
  const float* bo = (const float*)d_in[8];
  char* ws = (char*)d_ws;
  unsigned short* Xb    = (unsigned short*)(ws + XB_OFF);
  unsigned short* Wqkvt = (unsigned short*)(ws + WQKV_OFF);
  unsigned short* Wot   = (unsigned short*)(ws + WO_OFF);
  unsigned short* QKV   = (unsigned short*)(ws + QKV_OFF);
  unsigned short* AOb   = (unsigned short*)(ws + AOB_OFF);
  unsigned short* Qp = QKV;
  unsigned short* Kp = QKV + PLANE;
  unsigned short* Vp = QKV + 2 * PLANE;
  float* ksum = (float*)(ws + KSUM_OFF);
  float* qsum = (float*)(ws + QSUM_OFF);
  float* qsi  = (float*)(ws + QSI_OFF);
  float* kso  = (float*)(ws + KSO_OFF);
  float* esum = (float*)(ws + ESUM_OFF);
  float* si   = (float*)(ws + SI_OFF);
  float* sa   = (float*)(ws + SA_OFF);
  float* kvf  = (float*)(ws + KVF_OFF);
  float* kvp  = (float*)(ws + KVP_OFF);

  (void)hipMemsetAsync(ws + ST_OFF, 0, 81920, stream);  // zero small atomic accumulators
  conv_all_k<<<3072, 256, 0, stream>>>(x, Wq, Wk, Wv, Wo, Xb, Wqkvt, Wot);
  gemm8p<0><<<dim3(12, 64), 512, 0, stream>>>(Xb, Wqkvt, bq, bk, bv, qsum, ksum, (void*)QKV, 3072);
  flow1_k<<<NBH * 8, 256, 0, stream>>>(Qp, Kp, ksum, qsum, si, qsi, kso);
  flow2kv_k<<<NBH * 8, 256, 0, stream>>>(Qp, Kp, Vp, qsi, kso, sa, esum, kvp);
  kvred_k<<<1024, 256, 0, stream>>>(kvp, esum, kvf);
  outk_k<<<NBH * 16, 256, 0, stream>>>(Qp, kvf, si, sa, AOb);
  gemm8p<1><<<dim3(4, 64), 512, 0, stream>>>(AOb, Wot, bo, nullptr, nullptr, nullptr, nullptr, d_out, 1024);
}

// Round 20
// 297.552 us; speedup vs baseline: 1.2426x; 1.1267x over previous
//
#include <hip/hip_runtime.h>
#include <hip/hip_bf16.h>
#include <stdint.h>

#define SEQ    4096
#define DMODEL 1024
#define NHEAD  16
#define HDIM   64
#define NBATCH 4
#define NBH    (NBATCH*NHEAD)     // 64
#define MTOK   (NBATCH*SEQ)       // 16384
#define FEPS   1e-6f
#define PLANE  16777216u          // 16384*1024 shorts per Q/K/V plane

typedef float f32x4 __attribute__((ext_vector_type(4)));
typedef short bf16x8 __attribute__((ext_vector_type(8)));

// ---------- workspace layout (bytes) ----------
#define XB_OFF    0u                      // 16384*1024 bf16 = 33554432
#define WQKV_OFF  33554432u               // 3072*1024 bf16  = 6291456
#define WO_OFF    39845888u               // 1024*1024 bf16  = 2097152
#define QKV_OFF   41943040u               // 3 planes x 32MB = 100663296
#define AOB_OFF   142606336u              // 16384*1024 bf16 = 33554432
#define ST_OFF    176160768u
#define KSUM_OFF  (ST_OFF)                // 4096 f32
#define QSUM_OFF  (ST_OFF + 16384u)
#define QSI_OFF   (ST_OFF + 32768u)
#define KSO_OFF   (ST_OFF + 49152u)
#define ESUM_OFF  (ST_OFF + 65536u)       // 64 f32 (padded)
#define SI_OFF    (ST_OFF + 81920u)       // 262144 f32 = 1 MB
#define SA_OFF    (SI_OFF + 1048576u)
#define KVP_OFF   (SA_OFF + 1048576u)     // 8 MB partials

#define S_VMCNT(N) asm volatile("s_waitcnt vmcnt(" #N ")" ::: "memory")
#define BARRIER() do { __builtin_amdgcn_s_barrier(); asm volatile("" ::: "memory"); } while (0)

__device__ __forceinline__ unsigned short f2bf(float f) {
  __hip_bfloat16 h = __float2bfloat16(f);
  unsigned short u; __builtin_memcpy(&u, &h, 2); return u;
}
__device__ __forceinline__ float bf2f(unsigned short u) {
  union { unsigned u; float f; } x; x.u = ((unsigned)u) << 16; return x.f;
}
__device__ __forceinline__ void decode8(uint4 r, float* o) {
  o[0] = bf2f((unsigned short)(r.x & 0xffffu)); o[1] = bf2f((unsigned short)(r.x >> 16));
  o[2] = bf2f((unsigned short)(r.y & 0xffffu)); o[3] = bf2f((unsigned short)(r.y >> 16));
  o[4] = bf2f((unsigned short)(r.z & 0xffffu)); o[5] = bf2f((unsigned short)(r.z >> 16));
  o[6] = bf2f((unsigned short)(r.w & 0xffffu)); o[7] = bf2f((unsigned short)(r.w >> 16));
}
__device__ __forceinline__ void gll(const unsigned short* g, unsigned short* l) {
  __builtin_amdgcn_global_load_lds((const __attribute__((address_space(1))) void*)g,
      (__attribute__((address_space(3))) void*)l, 16, 0, 0);
}

// ---------- fused conversions: blocks 0-1023 = W transpose, 1024+ = x convert ----------
__global__ __launch_bounds__(256) void conv_all_k(const float* __restrict__ x,
                                                  const float* __restrict__ Wq, const float* __restrict__ Wk,
                                                  const float* __restrict__ Wv, const float* __restrict__ Wo,
                                                  unsigned short* __restrict__ xb,
                                                  unsigned short* __restrict__ Wqkvt,
                                                  unsigned short* __restrict__ Wot) {
  const int bx = blockIdx.x;
  if (bx < 1024) {
    __shared__ float tile[64][65];
    const int z = bx >> 8, tl = bx & 255;
    const float* W = (z == 0) ? Wq : (z == 1) ? Wk : (z == 2) ? Wv : Wo;
    unsigned short* dst = (z < 3) ? (Wqkvt + (size_t)z * 1024u * 1024u) : Wot;
    const int n0 = (tl & 15) * 64, k0 = (tl >> 4) * 64;
    const int tx = threadIdx.x & 63, ty = threadIdx.x >> 6;
    for (int i = ty; i < 64; i += 4)
      tile[i][tx] = W[(size_t)(k0 + i) * 1024 + n0 + tx];
    __syncthreads();
    for (int i = ty; i < 64; i += 4)
      dst[(size_t)(n0 + i) * 1024 + k0 + tx] = f2bf(tile[tx][i]);
  } else {
    const int n = MTOK * DMODEL;
    int i = ((bx - 1024) * 256 + threadIdx.x) * 4;
    const int stride = (gridDim.x - 1024) * 256 * 4;
    for (; i < n; i += stride) {
      float4 v = *(const float4*)(x + i);
      ushort4 o;
      o.x = f2bf(v.x); o.y = f2bf(v.y); o.z = f2bf(v.z); o.w = f2bf(v.w);
      *(ushort4*)(xb + i) = o;
    }
  }
}

// ---------- 256x256 GEMM, K=1024, BK=64, 4-phase/K-tile, single counted vmcnt ----------
// MODE 0: N=3072, bias+sigmoid epilogue, writes Q/K/V head-major planes
//         [bh][l][64] bf16 (plane = gc>>10), fused q/k per-column sums.
// MODE 1: N=1024, bias b0, fp32 row-major out.
template <int MODE>
__global__ __launch_bounds__(512, 2) void gemm8p(const unsigned short* __restrict__ A,
                                                 const unsigned short* __restrict__ Bt,
                                                 const float* __restrict__ b0,
                                                 const float* __restrict__ b1,
                                                 const float* __restrict__ b2,
                                                 float* __restrict__ qsum_g,
                                                 float* __restrict__ ksum_g,
                                                 void* __restrict__ C, int Ndim) {
  constexpr int Kd = 1024;
  constexpr int NT = Kd >> 6;
  __shared__ unsigned short sm[8 * 8192];                // 128 KiB
  const int tid = threadIdx.x;
  const int wid = tid >> 6, lane = tid & 63;
  const int wr = wid >> 2, wc = wid & 3;

  const int gx = gridDim.x;
  const int nwg = gx * gridDim.y;
  int wg = blockIdx.y * gx + blockIdx.x;
  wg = (wg & 7) * (nwg >> 3) + (wg >> 3);
  const int n0 = (wg % gx) * 256, m0 = (wg / gx) * 256;

  const int rl = lane & 15, kob = (lane >> 4) << 4;
  const int xs2 = (rl & 7) << 3;
  const int ca0 = (kob >> 1) ^ xs2;
  const int ca1 = (32 + (kob >> 1)) ^ xs2;
  const int brow0 = (wc & 1) * 64;
  const unsigned short* ArA = sm + wr * 8192 + rl * 64 + ca0;
  const unsigned short* ArB = sm + wr * 8192 + rl * 64 + ca1;
  const unsigned short* BrA = sm + (2 + (wc >> 1)) * 8192 + (brow0 + rl) * 64 + ca0;
  const unsigned short* BrB = sm + (2 + (wc >> 1)) * 8192 + (brow0 + rl) * 64 + ca1;

  const int srow = tid >> 3;
  const int scol = (((tid & 7) * 16) ^ ((srow & 7) << 4)) >> 1;
  const unsigned short* gA0 = A + (size_t)(m0 + srow) * Kd + scol;
  const unsigned short* gA1 = gA0 + 64 * Kd;
  const unsigned short* gA2 = gA0 + 128 * Kd;
  const unsigned short* gA3 = gA0 + 192 * Kd;
  const unsigned short* gB0 = Bt + (size_t)(n0 + srow) * Kd + scol;
  const unsigned short* gB1 = gB0 + 64 * Kd;
  const unsigned short* gB2 = gB0 + 128 * Kd;
  const unsigned short* gB3 = gB0 + 192 * Kd;
  unsigned short* ldst = sm + tid * 8;

  f32x4 acc[8][4];
#pragma unroll
  for (int i = 0; i < 8; ++i)
#pragma unroll
    for (int j = 0; j < 4; ++j) acc[i][j] = (f32x4){0.f, 0.f, 0.f, 0.f};

#define STG(g0, g1, R, T) do { \
    gll((g0) + (T) * 64, ldst + (R) * 8192); \
    gll((g1) + (T) * 64, ldst + (R) * 8192 + 4096); } while (0)

  STG(gA0, gA1, 0, 0); STG(gA2, gA3, 1, 0);
  STG(gB0, gB1, 2, 0); STG(gB2, gB3, 3, 0);
  STG(gA0, gA1, 4, 1); STG(gA2, gA3, 5, 1);
  S_VMCNT(4);
  BARRIER();

#define KBODY(U, BUF) do { \
    constexpr int BO = (BUF) * 32768; \
    bf16x8 a0[4][2], a1[4][2], b01[2][2], b23[2][2]; \
    _Pragma("unroll") for (int m = 0; m < 4; ++m) { \
      a0[m][0] = *(const bf16x8*)(ArA + BO + m * 1024); \
      a0[m][1] = *(const bf16x8*)(ArB + BO + m * 1024); } \
    _Pragma("unroll") for (int n = 0; n < 2; ++n) { \
      b01[n][0] = *(const bf16x8*)(BrA + BO + n * 1024); \
      b01[n][1] = *(const bf16x8*)(BrB + BO + n * 1024); } \
    if ((U) + 1 < NT) STG(gB0, gB1, (!(BUF)) * 4 + 2, (U) + 1); \
    BARRIER(); \
    __builtin_amdgcn_s_setprio(1); \
    _Pragma("unroll") for (int m = 0; m < 4; ++m) \
      _Pragma("unroll") for (int n = 0; n < 2; ++n) { \
        acc[m][n] = __builtin_amdgcn_mfma_f32_16x16x32_bf16(a0[m][0], b01[n][0], acc[m][n], 0, 0, 0); \
        acc[m][n] = __builtin_amdgcn_mfma_f32_16x16x32_bf16(a0[m][1], b01[n][1], acc[m][n], 0, 0, 0); } \
    __builtin_amdgcn_s_setprio(0); \
    BARRIER(); \
    _Pragma("unroll") for (int m = 0; m < 4; ++m) { \
      a1[m][0] = *(const bf16x8*)(ArA + BO + 4096 + m * 1024); \
      a1[m][1] = *(const bf16x8*)(ArB + BO + 4096 + m * 1024); } \
    if ((U) + 1 < NT) STG(gB2, gB3, (!(BUF)) * 4 + 3, (U) + 1); \
    BARRIER(); \
    __builtin_amdgcn_s_setprio(1); \
    _Pragma("unroll") for (int m = 0; m < 4; ++m) \
      _Pragma("unroll") for (int n = 0; n < 2; ++n) { \
        acc[4 + m][n] = __builtin_amdgcn_mfma_f32_16x16x32_bf16(a1[m][0], b01[n][0], acc[4 + m][n], 0, 0, 0); \
        acc[4 + m][n] = __builtin_amdgcn_mfma_f32_16x16x32_bf16(a1[m][1], b01[n][1], acc[4 + m][n], 0, 0, 0); } \
    __builtin_amdgcn_s_setprio(0); \
    BARRIER(); \
    _Pragma("unroll") for (int n = 0; n < 2; ++n) { \
      b23[n][0] = *(const bf16x8*)(BrA + BO + (2 + n) * 1024); \
      b23[n][1] = *(const bf16x8*)(BrB + BO + (2 + n) * 1024); } \
    if ((U) + 2 < NT) STG(gA0, gA1, (BUF) * 4, (U) + 2); \
    BARRIER(); \
    __builtin_amdgcn_s_setprio(1); \
    _Pragma("unroll") for (int m = 0; m < 4; ++m) \
      _Pragma("unroll") for (int n = 0; n < 2; ++n) { \
        acc[4 + m][2 + n] = __builtin_amdgcn_mfma_f32_16x16x32_bf16(a1[m][0], b23[n][0], acc[4 + m][2 + n], 0, 0, 0); \
        acc[4 + m][2 + n] = __builtin_amdgcn_mfma_f32_16x16x32_bf16(a1[m][1], b23[n][1], acc[4 + m][2 + n], 0, 0, 0); } \
    __builtin_amdgcn_s_setprio(0); \
    BARRIER(); \
    if ((U) + 2 < NT) STG(gA2, gA3, (BUF) * 4 + 1, (U) + 2); \
    BARRIER(); \
    __builtin_amdgcn_s_setprio(1); \
    _Pragma("unroll") for (int m = 0; m < 4; ++m) \
      _Pragma("unroll") for (int n = 0; n < 2; ++n) { \
        acc[m][2 + n] = __builtin_amdgcn_mfma_f32_16x16x32_bf16(a0[m][0], b23[n][0], acc[m][2 + n], 0, 0, 0); \
        acc[m][2 + n] = __builtin_amdgcn_mfma_f32_16x16x32_bf16(a0[m][1], b23[n][1], acc[m][2 + n], 0, 0, 0); } \
    __builtin_amdgcn_s_setprio(0); \
    if ((U) + 2 < NT) { S_VMCNT(4); } else { S_VMCNT(0); } \
    BARRIER(); \
  } while (0)

  for (int u = 0; u < NT; u += 2) {
    KBODY(u, 0);
    KBODY(u + 1, 1);
  }
#undef KBODY
#undef STG

  // ---- epilogue ----
  const int cr = (lane >> 4) * 4, cc = lane & 15;
  float cs[4] = {0.f, 0.f, 0.f, 0.f};
#pragma unroll
  for (int m = 0; m < 8; ++m)
#pragma unroll
    for (int n = 0; n < 4; ++n)
#pragma unroll
      for (int rr = 0; rr < 4; ++rr) {
        const int gr = m0 + wr * 128 + m * 16 + cr + rr;
        const int gc = n0 + wc * 64 + n * 16 + cc;
        float v = acc[m][n][rr];
        if (MODE == 0) {
          const float bias = (gc < 1024) ? b0[gc] : ((gc < 2048) ? b1[gc - 1024] : b2[gc - 2048]);
          v += bias;
          if (gc < 2048) v = 1.f / (1.f + __expf(-v));
          cs[n] += v;
          const size_t addr = (size_t)(gc >> 10) * PLANE +
                              ((size_t)(((gr >> 12) << 4) | ((gc >> 6) & 15)) * 4096 + (gr & 4095)) * 64 +
                              (gc & 63);
          ((unsigned short*)C)[addr] = f2bf(v);
        } else {
          v += b0[gc];
          ((float*)C)[(size_t)gr * Ndim + gc] = v;
        }
      }
  if (MODE == 0 && n0 < 2048) {
#pragma unroll
    for (int n = 0; n < 4; ++n) {
      cs[n] += __shfl_xor(cs[n], 16);
      cs[n] += __shfl_xor(cs[n], 32);
    }
    if (lane < 16) {
      const int b = m0 >> 12;
#pragma unroll
      for (int n = 0; n < 4; ++n) {
        const int gc = n0 + wc * 64 + n * 16 + lane;
        const int h = (gc & 1023) >> 6, d = gc & 63;
        float* tgt = (gc < 1024) ? qsum_g : ksum_g;
        atomicAdd(&tgt[((b << 4) + h) * 64 + d], cs[n]);
      }
    }
  }
}

// ---------- flow1: si, qsi, kso. Vectorized uint4 loads, 8-lane butterflies ----------
// lane = (r = lane>>3 in 0..7 rows, dg = lane&7 d-group); 4 waves x 128 rows.
__global__ __launch_bounds__(256) void flow1_k(const unsigned short* __restrict__ Qp,
                                               const unsigned short* __restrict__ Kp,
                                               const float* __restrict__ ksum, const float* __restrict__ qsum,
                                               float* __restrict__ si, float* __restrict__ qsi,
                                               float* __restrict__ kso) {
  const int bh = blockIdx.x >> 3, c = blockIdx.x & 7;
  const int t = threadIdx.x;
  const int w = t >> 6, lane = t & 63;
  const int r = lane >> 3, dg = lane & 7;
  const size_t hb = (size_t)bh * 262144;
  float ksv[8], qsv[8];
#pragma unroll
  for (int j = 0; j < 8; ++j) {
    ksv[j] = ksum[bh * 64 + dg * 8 + j] + FEPS;
    qsv[j] = qsum[bh * 64 + dg * 8 + j] + FEPS;
  }
  float qsi_acc[8] = {}, kso_acc[8] = {};
  const int l0w = c * 512 + w * 128;
  for (int l4 = 0; l4 < 128; l4 += 8) {
    const int l = l0w + l4 + r;
    const size_t off = hb + (size_t)l * 64 + dg * 8;
    const uint4 qr = *(const uint4*)(Qp + off);
    const uint4 kr = *(const uint4*)(Kp + off);
    float qd[8], kd[8];
    decode8(qr, qd); decode8(kr, kd);
    float dq = 0.f, dk = 0.f;
#pragma unroll
    for (int j = 0; j < 8; ++j) { dq += (qd[j] + FEPS) * ksv[j]; dk += (kd[j] + FEPS) * qsv[j]; }
#pragma unroll
    for (int m = 1; m < 8; m <<= 1) { dq += __shfl_xor(dq, m); dk += __shfl_xor(dk, m); }
    const float siv = 1.f / dq, sov = 1.f / dk;
    if (dg == 0) si[(size_t)bh * SEQ + l] = siv;
#pragma unroll
    for (int j = 0; j < 8; ++j) { qsi_acc[j] += qd[j] * siv; kso_acc[j] += kd[j] * sov; }
  }
#pragma unroll
  for (int m = 8; m < 64; m <<= 1)
#pragma unroll
    for (int j = 0; j < 8; ++j) {
      qsi_acc[j] += __shfl_xor(qsi_acc[j], m);
      kso_acc[j] += __shfl_xor(kso_acc[j], m);
    }
  if (lane < 8) {
#pragma unroll
    for (int j = 0; j < 8; ++j) {
      atomicAdd(&qsi[bh * 64 + lane * 8 + j], qsi_acc[j]);
      atomicAdd(&kso[bh * 64 + lane * 8 + j], kso_acc[j]);
    }
  }
}

// fused: sa/ee/esum (vectorized butterflies) + kv partial for the same 512 rows
__global__ __launch_bounds__(256) void flow2kv_k(const unsigned short* __restrict__ Qp,
                                                 const unsigned short* __restrict__ Kp,
                                                 const unsigned short* __restrict__ Vp,
                                                 const float* __restrict__ qsi, const float* __restrict__ kso,
                                                 float* __restrict__ sa, float* __restrict__ esum,
                                                 float* __restrict__ kvp) {
  const int bh = blockIdx.x >> 3, c = blockIdx.x & 7;
  __shared__ float eel[512];
  __shared__ float kch[32][64];
  __shared__ float vch[32][64];
  const int t = threadIdx.x;
  const int w = t >> 6, lane = t & 63;
  const size_t hb = (size_t)bh * 262144;

  // ---- phase A: sa, ee(->LDS), esum ----
  {
    const int r = lane >> 3, dg = lane & 7;
    float kov[8], qiv[8];
#pragma unroll
    for (int j = 0; j < 8; ++j) {
      kov[j] = kso[bh * 64 + dg * 8 + j] + FEPS;
      qiv[j] = qsi[bh * 64 + dg * 8 + j] + FEPS;
    }
    float es = 0.f;
    const int l0w = c * 512 + w * 128;
    for (int l4 = 0; l4 < 128; l4 += 8) {
      const int l = l0w + l4 + r;
      const size_t off = hb + (size_t)l * 64 + dg * 8;
      const uint4 qr = *(const uint4*)(Qp + off);
      const uint4 kr = *(const uint4*)(Kp + off);
      float qd[8], kd[8];
      decode8(qr, qd); decode8(kr, kd);
      float ds = 0.f, dr = 0.f;
#pragma unroll
      for (int j = 0; j < 8; ++j) { ds += (qd[j] + FEPS) * kov[j]; dr += (kd[j] + FEPS) * qiv[j]; }
#pragma unroll
      for (int m = 1; m < 8; m <<= 1) { ds += __shfl_xor(ds, m); dr += __shfl_xor(dr, m); }
      const float sig = 1.f / (1.f + __expf(-ds));
      const float cse = fminf(1.f, fmaxf(-1.f, dr));
      const float e = __expf(cse);
      if (dg == 0) {
        sa[(size_t)bh * SEQ + l] = sig;
        eel[w * 128 + l4 + r] = e;
        es += e;
      }
    }
#pragma unroll
    for (int m = 8; m < 64; m <<= 1) es += __shfl_xor(es, m);
    if (lane == 0) atomicAdd(&esum[bh], es);
  }
  __syncthreads();

  // ---- phase B: kv partial (k^T @ (v * ee)) over the same 512 rows ----
  const int sl = t >> 3, sd = (t & 7) * 8;
  const int d1 = (t >> 4) * 4, d2 = (t & 15) * 4;
  float acc[4][4] = {};
  for (int ch = 0; ch < 16; ++ch) {
    const int lloc = ch * 32 + sl;
    const size_t off = hb + (size_t)(c * 512 + lloc) * 64 + sd;
    const uint4 kr = *(const uint4*)(Kp + off);
    const uint4 vr = *(const uint4*)(Vp + off);
    const float cmp = eel[lloc];
    float kd[8], vd[8];
    decode8(kr, kd); decode8(vr, vd);
    __syncthreads();
    *(f32x4*)&kch[sl][sd]     = (f32x4){kd[0], kd[1], kd[2], kd[3]};
    *(f32x4*)&kch[sl][sd + 4] = (f32x4){kd[4], kd[5], kd[6], kd[7]};
    *(f32x4*)&vch[sl][sd]     = (f32x4){vd[0] * cmp, vd[1] * cmp, vd[2] * cmp, vd[3] * cmp};
    *(f32x4*)&vch[sl][sd + 4] = (f32x4){vd[4] * cmp, vd[5] * cmp, vd[6] * cmp, vd[7] * cmp};
    __syncthreads();
    for (int l = 0; l < 32; ++l) {
      const f32x4 ka = *(const f32x4*)&kch[l][d1];
      const f32x4 vb = *(const f32x4*)&vch[l][d2];
#pragma unroll
      for (int i = 0; i < 4; ++i)
#pragma unroll
        for (int j = 0; j < 4; ++j) acc[i][j] += ka[i] * vb[j];
    }
    __syncthreads();
  }
  float* dst = kvp + (size_t)blockIdx.x * 4096;
#pragma unroll
  for (int i = 0; i < 4; ++i)
    *(f32x4*)&dst[(d1 + i) * 64 + d2] = (f32x4){acc[i][0], acc[i][1], acc[i][2], acc[i][3]};
}

// out = (Q @ kv) row-scaled by si*sa -> bf16 AOb token-major. MFMA + fused kvred.
// grid NBH*16, 256 thr = 4 waves; per block 256 rows; kvT bf16 in LDS (swizzled).
__global__ __launch_bounds__(256) void outk_k(const unsigned short* __restrict__ Qp,
                                              const float* __restrict__ kvp, const float* __restrict__ esum,
                                              const float* __restrict__ si, const float* __restrict__ sa,
                                              unsigned short* __restrict__ AOb) {
  const int bh = blockIdx.x >> 4, lc = blockIdx.x & 15;
  const int b = bh >> 4, h = bh & 15;
  __shared__ unsigned short kvT[4096];                   // [d][dd] bf16, 8-blk XOR swizzle
  const int t = threadIdx.x;
  const int w = t >> 6, lane = t & 63;
  const float Ls = 4096.f / esum[bh];
  // fused kvred: sum 8 partials, scale, transpose+convert into LDS
  for (int i = t; i < 4096; i += 256) {
    float s = 0.f;
#pragma unroll
    for (int cN = 0; cN < 8; ++cN) s += kvp[((size_t)(bh * 8 + cN)) * 4096 + i];
    const int dd = i >> 6, d = i & 63;
    kvT[d * 64 + (dd ^ ((d & 7) << 3))] = f2bf(s * Ls);
  }
  __syncthreads();

  const int rl = lane & 15, g = lane >> 4;               // g = 0..3 (k-group)
  const size_t hb = (size_t)bh * 262144;
  const int l0 = lc * 256 + w * 64;

  bf16x8 a[4][2], bf[4][2];
#pragma unroll
  for (int m = 0; m < 4; ++m) {
    const size_t q0 = hb + (size_t)(l0 + m * 16 + rl) * 64 + g * 8;
    a[m][0] = *(const bf16x8*)(Qp + q0);
    a[m][1] = *(const bf16x8*)(Qp + q0 + 32);
  }
#pragma unroll
  for (int n = 0; n < 4; ++n) {
    const int r = n * 16 + rl;
    const int sw = (r & 7) << 3;
    bf[n][0] = *(const bf16x8*)(kvT + r * 64 + ((g * 8) ^ sw));
    bf[n][1] = *(const bf16x8*)(kvT + r * 64 + ((32 + g * 8) ^ sw));
  }
  f32x4 acc[4][4];
#pragma unroll
  for (int i = 0; i < 4; ++i)
#pragma unroll
    for (int j = 0; j < 4; ++j) acc[i][j] = (f32x4){0.f, 0.f, 0.f, 0.f};
#pragma unroll
  for (int m = 0; m < 4; ++m)
#pragma unroll
    for (int n = 0; n < 4; ++n) {
      acc[m][n] = __builtin_amdgcn_mfma_f32_16x16x32_bf16(a[m][0], bf[n][0], acc[m][n], 0, 0, 0);
      acc[m][n] = __builtin_amdgcn_mfma_f32_16x16x32_bf16(a[m][1], bf[n][1], acc[m][n], 0, 0, 0);
    }

  const int cr = (lane >> 4) * 4, cc = lane & 15;
#pragma unroll
  for (int m = 0; m < 4; ++m)
#pragma unroll
    for (int rr = 0; rr < 4; ++rr) {
      const int l = l0 + m * 16 + cr + rr;
      const size_t sidx = (size_t)bh * SEQ + l;
      const float sc = si[sidx] * sa[sidx];
      unsigned short* orow = AOb + (size_t)(b * SEQ + l) * 1024 + h * 64 + cc;
#pragma unroll
      for (int n = 0; n < 4; ++n)
        orow[n * 16] = f2bf(acc[m][n][rr] * sc);
    }
}

extern "C" void kernel_launch(void* const* d_in, const int* in_sizes, int n_in,
                              void* d_out, int out_size, void* d_ws, size_t ws_size,
                              hipStream_t stream) {
  const float* x  = (const float*)d_in[0];
  const float* Wq = (const float*)d_in[1];
  const float* bq = (const float*)d_in[2];
  const float* Wk = (const float*)d_in[3];
  const float* bk = (const float*)d_in[4];
  const float* Wv = (const float*)d_in[5];
  const float* bv = (const float*)d_in[6];
  const float* Wo = (const float*)d_in[7];
  const float* bo = (const float*)d_in[8];
  char* ws = (char*)d_ws;
  unsigned short* Xb    = (unsigned short*)(ws + XB_OFF);
  unsigned short* Wqkvt = (unsigned short*)(ws + WQKV_OFF);
  unsigned short* Wot   = (unsigned short*)(ws + WO_OFF);
  unsigned short* QKV   = (unsigned short*)(ws + QKV_OFF);
  unsigned short* AOb   = (unsigned short*)(ws + AOB_OFF);
  unsigned short* Qp = QKV;
  unsigned short* Kp = QKV + PLANE;
  unsigned short* Vp = QKV + 2 * PLANE;
  float* ksum = (float*)(ws + KSUM_OFF);
  float* qsum = (float*)(ws + QSUM_OFF);
  float* qsi  = (float*)(ws + QSI_OFF);
  float* kso  = (float*)(ws + KSO_OFF);
  float* esum = (float*)(ws + ESUM_OFF);
  float* si   = (float*)(ws + SI_OFF);
  float* sa   = (float*)(ws + SA_OFF);
  float* kvp  = (float*)(ws + KVP_OFF);

  (void)hipMemsetAsync(ws + ST_OFF, 0, 81920, stream);  // zero small atomic accumulators
  conv_all_k<<<3072, 256, 0, stream>>>(x, Wq, Wk, Wv, Wo, Xb, Wqkvt, Wot);
  gemm8p<0><<<dim3(12, 64), 512, 0, stream>>>(Xb, Wqkvt, bq, bk, bv, qsum, ksum, (void*)QKV, 3072);
  flow1_k<<<NBH * 8, 256, 0, stream>>>(Qp, Kp, ksum, qsum, si, qsi, kso);
  flow2kv_k<<<NBH * 8, 256, 0, stream>>>(Qp, Kp, Vp, qsi, kso, sa, esum, kvp);
  outk_k<<<NBH * 16, 256, 0, stream>>>(Qp, kvp, esum, si, sa, AOb);
  gemm8p<1><<<dim3(4, 64), 512, 0, stream>>>(AOb, Wot, bo, nullptr, nullptr, nullptr, nullptr, d_out, 1024);
}

// Round 21
// 276.722 us; speedup vs baseline: 1.3361x; 1.0753x over previous
//
#include <hip/hip_runtime.h>
#include <hip/hip_bf16.h>
#include <stdint.h>

#define SEQ    4096
#define DMODEL 1024
#define NHEAD  16
#define HDIM   64
#define NBATCH 4
#define NBH    (NBATCH*NHEAD)     // 64
#define MTOK   (NBATCH*SEQ)       // 16384
#define FEPS   1e-6f
#define PLANE  16777216u          // 16384*1024 shorts per Q/K/V plane

typedef float f32x4 __attribute__((ext_vector_type(4)));
typedef short bf16x8 __attribute__((ext_vector_type(8)));

// ---------- workspace layout (bytes) ----------
#define XB_OFF    0u                      // 16384*1024 bf16 = 33554432
#define WQKV_OFF  33554432u               // 3072*1024 bf16  = 6291456
#define WO_OFF    39845888u               // 1024*1024 bf16  = 2097152
#define QKV_OFF   41943040u               // 3 planes x 32MB = 100663296
#define AOB_OFF   142606336u              // 16384*1024 bf16 = 33554432
#define ST_OFF    176160768u
#define KSUM_OFF  (ST_OFF)                // 4096 f32
#define QSUM_OFF  (ST_OFF + 16384u)
#define QSI_OFF   (ST_OFF + 32768u)
#define KSO_OFF   (ST_OFF + 49152u)
#define ESUM_OFF  (ST_OFF + 65536u)       // 64 f32 (padded)
#define SI_OFF    (ST_OFF + 81920u)       // 262144 f32 = 1 MB
#define SA_OFF    (SI_OFF + 1048576u)
#define KVP_OFF   (SA_OFF + 1048576u)     // 8 MB partials

#define S_VMCNT(N) asm volatile("s_waitcnt vmcnt(" #N ")" ::: "memory")
#define BARRIER() do { __builtin_amdgcn_s_barrier(); asm volatile("" ::: "memory"); } while (0)

__device__ __forceinline__ unsigned short f2bf(float f) {
  __hip_bfloat16 h = __float2bfloat16(f);
  unsigned short u; __builtin_memcpy(&u, &h, 2); return u;
}
__device__ __forceinline__ float bf2f(unsigned short u) {
  union { unsigned u; float f; } x; x.u = ((unsigned)u) << 16; return x.f;
}
__device__ __forceinline__ void decode8(uint4 r, float* o) {
  o[0] = bf2f((unsigned short)(r.x & 0xffffu)); o[1] = bf2f((unsigned short)(r.x >> 16));
  o[2] = bf2f((unsigned short)(r.y & 0xffffu)); o[3] = bf2f((unsigned short)(r.y >> 16));
  o[4] = bf2f((unsigned short)(r.z & 0xffffu)); o[5] = bf2f((unsigned short)(r.z >> 16));
  o[6] = bf2f((unsigned short)(r.w & 0xffffu)); o[7] = bf2f((unsigned short)(r.w >> 16));
}
__device__ __forceinline__ void gll(const unsigned short* g, unsigned short* l) {
  __builtin_amdgcn_global_load_lds((const __attribute__((address_space(1))) void*)g,
      (__attribute__((address_space(3))) void*)l, 16, 0, 0);
}

// ---------- fused conversions: blocks 0-1023 = W transpose, 1024+ = x convert ----------
__global__ __launch_bounds__(256) void conv_all_k(const float* __restrict__ x,
                                                  const float* __restrict__ Wq, const float* __restrict__ Wk,
                                                  const float* __restrict__ Wv, const float* __restrict__ Wo,
                                                  unsigned short* __restrict__ xb,
                                                  unsigned short* __restrict__ Wqkvt,
                                                  unsigned short* __restrict__ Wot) {
  const int bx = blockIdx.x;
  if (bx < 1024) {
    __shared__ float tile[64][65];
    const int z = bx >> 8, tl = bx & 255;
    const float* W = (z == 0) ? Wq : (z == 1) ? Wk : (z == 2) ? Wv : Wo;
    unsigned short* dst = (z < 3) ? (Wqkvt + (size_t)z * 1024u * 1024u) : Wot;
    const int n0 = (tl & 15) * 64, k0 = (tl >> 4) * 64;
    const int tx = threadIdx.x & 63, ty = threadIdx.x >> 6;
    for (int i = ty; i < 64; i += 4)
      tile[i][tx] = W[(size_t)(k0 + i) * 1024 + n0 + tx];
    __syncthreads();
    for (int i = ty; i < 64; i += 4)
      dst[(size_t)(n0 + i) * 1024 + k0 + tx] = f2bf(tile[tx][i]);
  } else {
    const int n = MTOK * DMODEL;
    int i = ((bx - 1024) * 256 + threadIdx.x) * 4;
    const int stride = (gridDim.x - 1024) * 256 * 4;
    for (; i < n; i += stride) {
      float4 v = *(const float4*)(x + i);
      ushort4 o;
      o.x = f2bf(v.x); o.y = f2bf(v.y); o.z = f2bf(v.z); o.w = f2bf(v.w);
      *(ushort4*)(xb + i) = o;
    }
  }
}

// ---------- 256x256 GEMM, K=1024, BK=64, 4-phase/K-tile, single counted vmcnt ----------
// MODE 0: N=3072, bias+sigmoid epilogue, writes Q/K/V head-major planes
//         [bh][l][64] bf16 (plane = gc>>10), fused q/k per-column sums.
// MODE 1: N=1024, bias b0, fp32 row-major out.
template <int MODE>
__global__ __launch_bounds__(512, 2) void gemm8p(const unsigned short* __restrict__ A,
                                                 const unsigned short* __restrict__ Bt,
                                                 const float* __restrict__ b0,
                                                 const float* __restrict__ b1,
                                                 const float* __restrict__ b2,
                                                 float* __restrict__ qsum_g,
                                                 float* __restrict__ ksum_g,
                                                 void* __restrict__ C, int Ndim) {
  constexpr int Kd = 1024;
  constexpr int NT = Kd >> 6;
  __shared__ unsigned short sm[8 * 8192];                // 128 KiB
  const int tid = threadIdx.x;
  const int wid = tid >> 6, lane = tid & 63;
  const int wr = wid >> 2, wc = wid & 3;

  const int gx = gridDim.x;
  const int nwg = gx * gridDim.y;
  int wg = blockIdx.y * gx + blockIdx.x;
  wg = (wg & 7) * (nwg >> 3) + (wg >> 3);
  const int n0 = (wg % gx) * 256, m0 = (wg / gx) * 256;

  const int rl = lane & 15, kob = (lane >> 4) << 4;
  const int xs2 = (rl & 7) << 3;
  const int ca0 = (kob >> 1) ^ xs2;
  const int ca1 = (32 + (kob >> 1)) ^ xs2;
  const int brow0 = (wc & 1) * 64;
  const unsigned short* ArA = sm + wr * 8192 + rl * 64 + ca0;
  const unsigned short* ArB = sm + wr * 8192 + rl * 64 + ca1;
  const unsigned short* BrA = sm + (2 + (wc >> 1)) * 8192 + (brow0 + rl) * 64 + ca0;
  const unsigned short* BrB = sm + (2 + (wc >> 1)) * 8192 + (brow0 + rl) * 64 + ca1;

  const int srow = tid >> 3;
  const int scol = (((tid & 7) * 16) ^ ((srow & 7) << 4)) >> 1;
  const unsigned short* gA0 = A + (size_t)(m0 + srow) * Kd + scol;
  const unsigned short* gA1 = gA0 + 64 * Kd;
  const unsigned short* gA2 = gA0 + 128 * Kd;
  const unsigned short* gA3 = gA0 + 192 * Kd;
  const unsigned short* gB0 = Bt + (size_t)(n0 + srow) * Kd + scol;
  const unsigned short* gB1 = gB0 + 64 * Kd;
  const unsigned short* gB2 = gB0 + 128 * Kd;
  const unsigned short* gB3 = gB0 + 192 * Kd;
  unsigned short* ldst = sm + tid * 8;

  f32x4 acc[8][4];
#pragma unroll
  for (int i = 0; i < 8; ++i)
#pragma unroll
    for (int j = 0; j < 4; ++j) acc[i][j] = (f32x4){0.f, 0.f, 0.f, 0.f};

#define STG(g0, g1, R, T) do { \
    gll((g0) + (T) * 64, ldst + (R) * 8192); \
    gll((g1) + (T) * 64, ldst + (R) * 8192 + 4096); } while (0)

  STG(gA0, gA1, 0, 0); STG(gA2, gA3, 1, 0);
  STG(gB0, gB1, 2, 0); STG(gB2, gB3, 3, 0);
  STG(gA0, gA1, 4, 1); STG(gA2, gA3, 5, 1);
  S_VMCNT(4);
  BARRIER();

#define KBODY(U, BUF) do { \
    constexpr int BO = (BUF) * 32768; \
    bf16x8 a0[4][2], a1[4][2], b01[2][2], b23[2][2]; \
    _Pragma("unroll") for (int m = 0; m < 4; ++m) { \
      a0[m][0] = *(const bf16x8*)(ArA + BO + m * 1024); \
      a0[m][1] = *(const bf16x8*)(ArB + BO + m * 1024); } \
    _Pragma("unroll") for (int n = 0; n < 2; ++n) { \
      b01[n][0] = *(const bf16x8*)(BrA + BO + n * 1024); \
      b01[n][1] = *(const bf16x8*)(BrB + BO + n * 1024); } \
    if ((U) + 1 < NT) STG(gB0, gB1, (!(BUF)) * 4 + 2, (U) + 1); \
    BARRIER(); \
    __builtin_amdgcn_s_setprio(1); \
    _Pragma("unroll") for (int m = 0; m < 4; ++m) \
      _Pragma("unroll") for (int n = 0; n < 2; ++n) { \
        acc[m][n] = __builtin_amdgcn_mfma_f32_16x16x32_bf16(a0[m][0], b01[n][0], acc[m][n], 0, 0, 0); \
        acc[m][n] = __builtin_amdgcn_mfma_f32_16x16x32_bf16(a0[m][1], b01[n][1], acc[m][n], 0, 0, 0); } \
    __builtin_amdgcn_s_setprio(0); \
    BARRIER(); \
    _Pragma("unroll") for (int m = 0; m < 4; ++m) { \
      a1[m][0] = *(const bf16x8*)(ArA + BO + 4096 + m * 1024); \
      a1[m][1] = *(const bf16x8*)(ArB + BO + 4096 + m * 1024); } \
    if ((U) + 1 < NT) STG(gB2, gB3, (!(BUF)) * 4 + 3, (U) + 1); \
    BARRIER(); \
    __builtin_amdgcn_s_setprio(1); \
    _Pragma("unroll") for (int m = 0; m < 4; ++m) \
      _Pragma("unroll") for (int n = 0; n < 2; ++n) { \
        acc[4 + m][n] = __builtin_amdgcn_mfma_f32_16x16x32_bf16(a1[m][0], b01[n][0], acc[4 + m][n], 0, 0, 0); \
        acc[4 + m][n] = __builtin_amdgcn_mfma_f32_16x16x32_bf16(a1[m][1], b01[n][1], acc[4 + m][n], 0, 0, 0); } \
    __builtin_amdgcn_s_setprio(0); \
    BARRIER(); \
    _Pragma("unroll") for (int n = 0; n < 2; ++n) { \
      b23[n][0] = *(const bf16x8*)(BrA + BO + (2 + n) * 1024); \
      b23[n][1] = *(const bf16x8*)(BrB + BO + (2 + n) * 1024); } \
    if ((U) + 2 < NT) STG(gA0, gA1, (BUF) * 4, (U) + 2); \
    BARRIER(); \
    __builtin_amdgcn_s_setprio(1); \
    _Pragma("unroll") for (int m = 0; m < 4; ++m) \
      _Pragma("unroll") for (int n = 0; n < 2; ++n) { \
        acc[4 + m][2 + n] = __builtin_amdgcn_mfma_f32_16x16x32_bf16(a1[m][0], b23[n][0], acc[4 + m][2 + n], 0, 0, 0); \
        acc[4 + m][2 + n] = __builtin_amdgcn_mfma_f32_16x16x32_bf16(a1[m][1], b23[n][1], acc[4 + m][2 + n], 0, 0, 0); } \
    __builtin_amdgcn_s_setprio(0); \
    BARRIER(); \
    if ((U) + 2 < NT) STG(gA2, gA3, (BUF) * 4 + 1, (U) + 2); \
    BARRIER(); \
    __builtin_amdgcn_s_setprio(1); \
    _Pragma("unroll") for (int m = 0; m < 4; ++m) \
      _Pragma("unroll") for (int n = 0; n < 2; ++n) { \
        acc[m][2 + n] = __builtin_amdgcn_mfma_f32_16x16x32_bf16(a0[m][0], b23[n][0], acc[m][2 + n], 0, 0, 0); \
        acc[m][2 + n] = __builtin_amdgcn_mfma_f32_16x16x32_bf16(a0[m][1], b23[n][1], acc[m][2 + n], 0, 0, 0); } \
    __builtin_amdgcn_s_setprio(0); \
    if ((U) + 2 < NT) { S_VMCNT(4); } else { S_VMCNT(0); } \
    BARRIER(); \
  } while (0)

  for (int u = 0; u < NT; u += 2) {
    KBODY(u, 0);
    KBODY(u + 1, 1);
  }
#undef KBODY
#undef STG

  // ---- epilogue ----
  const int cr = (lane >> 4) * 4, cc = lane & 15;
  float cs[4] = {0.f, 0.f, 0.f, 0.f};
#pragma unroll
  for (int m = 0; m < 8; ++m)
#pragma unroll
    for (int n = 0; n < 4; ++n)
#pragma unroll
      for (int rr = 0; rr < 4; ++rr) {
        const int gr = m0 + wr * 128 + m * 16 + cr + rr;
        const int gc = n0 + wc * 64 + n * 16 + cc;
        float v = acc[m][n][rr];
        if (MODE == 0) {
          const float bias = (gc < 1024) ? b0[gc] : ((gc < 2048) ? b1[gc - 1024] : b2[gc - 2048]);
          v += bias;
          if (gc < 2048) v = 1.f / (1.f + __expf(-v));
          cs[n] += v;
          const size_t addr = (size_t)(gc >> 10) * PLANE +
                              ((size_t)(((gr >> 12) << 4) | ((gc >> 6) & 15)) * 4096 + (gr & 4095)) * 64 +
                              (gc & 63);
          ((unsigned short*)C)[addr] = f2bf(v);
        } else {
          v += b0[gc];
          ((float*)C)[(size_t)gr * Ndim + gc] = v;
        }
      }
  if (MODE == 0 && n0 < 2048) {
#pragma unroll
    for (int n = 0; n < 4; ++n) {
      cs[n] += __shfl_xor(cs[n], 16);
      cs[n] += __shfl_xor(cs[n], 32);
    }
    if (lane < 16) {
      const int b = m0 >> 12;
#pragma unroll
      for (int n = 0; n < 4; ++n) {
        const int gc = n0 + wc * 64 + n * 16 + lane;
        const int h = (gc & 1023) >> 6, d = gc & 63;
        float* tgt = (gc < 1024) ? qsum_g : ksum_g;
        atomicAdd(&tgt[((b << 4) + h) * 64 + d], cs[n]);
      }
    }
  }
}

// ---------- flow1: si, qsi, kso. Vectorized uint4 loads, 8-lane butterflies ----------
__global__ __launch_bounds__(256) void flow1_k(const unsigned short* __restrict__ Qp,
                                               const unsigned short* __restrict__ Kp,
                                               const float* __restrict__ ksum, const float* __restrict__ qsum,
                                               float* __restrict__ si, float* __restrict__ qsi,
                                               float* __restrict__ kso) {
  const int bh = blockIdx.x >> 3, c = blockIdx.x & 7;
  const int t = threadIdx.x;
  const int w = t >> 6, lane = t & 63;
  const int r = lane >> 3, dg = lane & 7;
  const size_t hb = (size_t)bh * 262144;
  float ksv[8], qsv[8];
#pragma unroll
  for (int j = 0; j < 8; ++j) {
    ksv[j] = ksum[bh * 64 + dg * 8 + j] + FEPS;
    qsv[j] = qsum[bh * 64 + dg * 8 + j] + FEPS;
  }
  float qsi_acc[8] = {}, kso_acc[8] = {};
  const int l0w = c * 512 + w * 128;
  for (int l4 = 0; l4 < 128; l4 += 8) {
    const int l = l0w + l4 + r;
    const size_t off = hb + (size_t)l * 64 + dg * 8;
    const uint4 qr = *(const uint4*)(Qp + off);
    const uint4 kr = *(const uint4*)(Kp + off);
    float qd[8], kd[8];
    decode8(qr, qd); decode8(kr, kd);
    float dq = 0.f, dk = 0.f;
#pragma unroll
    for (int j = 0; j < 8; ++j) { dq += (qd[j] + FEPS) * ksv[j]; dk += (kd[j] + FEPS) * qsv[j]; }
#pragma unroll
    for (int m = 1; m < 8; m <<= 1) { dq += __shfl_xor(dq, m); dk += __shfl_xor(dk, m); }
    const float siv = 1.f / dq, sov = 1.f / dk;
    if (dg == 0) si[(size_t)bh * SEQ + l] = siv;
#pragma unroll
    for (int j = 0; j < 8; ++j) { qsi_acc[j] += qd[j] * siv; kso_acc[j] += kd[j] * sov; }
  }
#pragma unroll
  for (int m = 8; m < 64; m <<= 1)
#pragma unroll
    for (int j = 0; j < 8; ++j) {
      qsi_acc[j] += __shfl_xor(qsi_acc[j], m);
      kso_acc[j] += __shfl_xor(kso_acc[j], m);
    }
  if (lane < 8) {
#pragma unroll
    for (int j = 0; j < 8; ++j) {
      atomicAdd(&qsi[bh * 64 + lane * 8 + j], qsi_acc[j]);
      atomicAdd(&kso[bh * 64 + lane * 8 + j], kso_acc[j]);
    }
  }
}

// fused: sa/ee/esum (vectorized butterflies) + MFMA kv partial for the same 512 rows.
// Phase B: per 32-row chunk stage transposed bf16 tiles kT[d][l], vT[d][l] (V*ee),
// swizzle col = l ^ (((d>>3)&3)<<3); 4 waves x (1 A-frag + 4 B-frags + 4 MFMA)/chunk.
__global__ __launch_bounds__(256) void flow2kv_k(const unsigned short* __restrict__ Qp,
                                                 const unsigned short* __restrict__ Kp,
                                                 const unsigned short* __restrict__ Vp,
                                                 const float* __restrict__ qsi, const float* __restrict__ kso,
                                                 float* __restrict__ sa, float* __restrict__ esum,
                                                 float* __restrict__ kvp) {
  const int bh = blockIdx.x >> 3, c = blockIdx.x & 7;
  __shared__ float eel[512];
  __shared__ unsigned short kT[2048];                    // [64][32] bf16, swizzled
  __shared__ unsigned short vT[2048];
  const int t = threadIdx.x;
  const int w = t >> 6, lane = t & 63;
  const size_t hb = (size_t)bh * 262144;

  // ---- phase A: sa, ee(->LDS), esum ----
  {
    const int r = lane >> 3, dg = lane & 7;
    float kov[8], qiv[8];
#pragma unroll
    for (int j = 0; j < 8; ++j) {
      kov[j] = kso[bh * 64 + dg * 8 + j] + FEPS;
      qiv[j] = qsi[bh * 64 + dg * 8 + j] + FEPS;
    }
    float es = 0.f;
    const int l0w = c * 512 + w * 128;
    for (int l4 = 0; l4 < 128; l4 += 8) {
      const int l = l0w + l4 + r;
      const size_t off = hb + (size_t)l * 64 + dg * 8;
      const uint4 qr = *(const uint4*)(Qp + off);
      const uint4 kr = *(const uint4*)(Kp + off);
      float qd[8], kd[8];
      decode8(qr, qd); decode8(kr, kd);
      float ds = 0.f, dr = 0.f;
#pragma unroll
      for (int j = 0; j < 8; ++j) { ds += (qd[j] + FEPS) * kov[j]; dr += (kd[j] + FEPS) * qiv[j]; }
#pragma unroll
      for (int m = 1; m < 8; m <<= 1) { ds += __shfl_xor(ds, m); dr += __shfl_xor(dr, m); }
      const float sig = 1.f / (1.f + __expf(-ds));
      const float cse = fminf(1.f, fmaxf(-1.f, dr));
      const float e = __expf(cse);
      if (dg == 0) {
        sa[(size_t)bh * SEQ + l] = sig;
        eel[w * 128 + l4 + r] = e;
        es += e;
      }
    }
#pragma unroll
    for (int m = 8; m < 64; m <<= 1) es += __shfl_xor(es, m);
    if (lane == 0) atomicAdd(&esum[bh], es);
  }
  __syncthreads();

  // ---- phase B: kv partial via MFMA on transposed bf16 tiles ----
  const int sl = t >> 3, sd = (t & 7) * 8;               // staging: row sl, d-group sd
  const int rl2 = lane & 15, g = lane >> 4;              // frag lane decomposition
  f32x4 acc[4];
#pragma unroll
  for (int j = 0; j < 4; ++j) acc[j] = (f32x4){0.f, 0.f, 0.f, 0.f};

  const int da = w * 16 + rl2;                           // A-frag row (dd)
  const int colA = (g * 8) ^ (((da >> 3) & 3) << 3);

  for (int ch = 0; ch < 16; ++ch) {
    const int lloc = ch * 32 + sl;
    const size_t off = hb + (size_t)(c * 512 + lloc) * 64 + sd;
    const uint4 kr = *(const uint4*)(Kp + off);
    const uint4 vr = *(const uint4*)(Vp + off);
    const float cmp = eel[lloc];
    unsigned short ks8[8];
    *(uint4*)ks8 = kr;                                   // K passes through as raw bf16
    float vd[8]; decode8(vr, vd);
    __syncthreads();                                     // prev chunk's frags consumed
#pragma unroll
    for (int j = 0; j < 8; ++j) {
      const int d = sd + j;
      const int col = sl ^ (((d >> 3) & 3) << 3);
      kT[d * 32 + col] = ks8[j];
      vT[d * 32 + col] = f2bf(vd[j] * cmp);
    }
    __syncthreads();
    const bf16x8 a = *(const bf16x8*)(kT + da * 32 + colA);
#pragma unroll
    for (int n = 0; n < 4; ++n) {
      const int db = n * 16 + rl2;
      const int colB = (g * 8) ^ (((db >> 3) & 3) << 3);
      const bf16x8 b = *(const bf16x8*)(vT + db * 32 + colB);
      acc[n] = __builtin_amdgcn_mfma_f32_16x16x32_bf16(a, b, acc[n], 0, 0, 0);
    }
  }
  float* dst = kvp + (size_t)blockIdx.x * 4096;
  const int cr = (lane >> 4) * 4, cc = lane & 15;
#pragma unroll
  for (int n = 0; n < 4; ++n)
#pragma unroll
    for (int rr = 0; rr < 4; ++rr)
      dst[(w * 16 + cr + rr) * 64 + n * 16 + cc] = acc[n][rr];
}

// out = (Q @ kv) row-scaled by si*sa -> bf16 AOb token-major. MFMA + fused kvred.
__global__ __launch_bounds__(256) void outk_k(const unsigned short* __restrict__ Qp,
                                              const float* __restrict__ kvp, const float* __restrict__ esum,
                                              const float* __restrict__ si, const float* __restrict__ sa,
                                              unsigned short* __restrict__ AOb) {
  const int bh = blockIdx.x >> 4, lc = blockIdx.x & 15;
  const int b = bh >> 4, h = bh & 15;
  __shared__ unsigned short kvT[4096];                   // [d][dd] bf16, 8-blk XOR swizzle
  const int t = threadIdx.x;
  const int w = t >> 6, lane = t & 63;
  const float Ls = 4096.f / esum[bh];
  for (int i = t; i < 4096; i += 256) {
    float s = 0.f;
#pragma unroll
    for (int cN = 0; cN < 8; ++cN) s += kvp[((size_t)(bh * 8 + cN)) * 4096 + i];
    const int dd = i >> 6, d = i & 63;
    kvT[d * 64 + (dd ^ ((d & 7) << 3))] = f2bf(s * Ls);
  }
  __syncthreads();

  const int rl = lane & 15, g = lane >> 4;
  const size_t hb = (size_t)bh * 262144;
  const int l0 = lc * 256 + w * 64;

  bf16x8 a[4][2], bf[4][2];
#pragma unroll
  for (int m = 0; m < 4; ++m) {
    const size_t q0 = hb + (size_t)(l0 + m * 16 + rl) * 64 + g * 8;
    a[m][0] = *(const bf16x8*)(Qp + q0);
    a[m][1] = *(const bf16x8*)(Qp + q0 + 32);
  }
#pragma unroll
  for (int n = 0; n < 4; ++n) {
    const int r = n * 16 + rl;
    const int sw = (r & 7) << 3;
    bf[n][0] = *(const bf16x8*)(kvT + r * 64 + ((g * 8) ^ sw));
    bf[n][1] = *(const bf16x8*)(kvT + r * 64 + ((32 + g * 8) ^ sw));
  }
  f32x4 acc[4][4];
#pragma unroll
  for (int i = 0; i < 4; ++i)
#pragma unroll
    for (int j = 0; j < 4; ++j) acc[i][j] = (f32x4){0.f, 0.f, 0.f, 0.f};
#pragma unroll
  for (int m = 0; m < 4; ++m)
#pragma unroll
    for (int n = 0; n < 4; ++n) {
      acc[m][n] = __builtin_amdgcn_mfma_f32_16x16x32_bf16(a[m][0], bf[n][0], acc[m][n], 0, 0, 0);
      acc[m][n] = __builtin_amdgcn_mfma_f32_16x16x32_bf16(a[m][1], bf[n][1], acc[m][n], 0, 0, 0);
    }

  const int cr = (lane >> 4) * 4, cc = lane & 15;
#pragma unroll
  for (int m = 0; m < 4; ++m)
#pragma unroll
    for (int rr = 0; rr < 4; ++rr) {
      const int l = l0 + m * 16 + cr + rr;
      const size_t sidx = (size_t)bh * SEQ + l;
      const float sc = si[sidx] * sa[sidx];
      unsigned short* orow = AOb + (size_t)(b * SEQ + l) * 1024 + h * 64 + cc;
#pragma unroll
      for (int n = 0; n < 4; ++n)
        orow[n * 16] = f2bf(acc[m][n][rr] * sc);
    }
}

extern "C" void kernel_launch(void* const* d_in, const int* in_sizes, int n_in,
                              void* d_out, int out_size, void* d_ws, size_t ws_size,
                              hipStream_t stream) {
  const float* x  = (const float*)d_in[0];
  const float* Wq = (const float*)d_in[1];
  const float* bq = (const float*)d_in[2];
  const float* Wk = (const float*)d_in[3];
  const float* bk = (const float*)d_in[4];
  const float* Wv = (const float*)d_in[5];
  const float* bv = (const float*)d_in[6];
  const float* Wo = (const float*)d_in[7];
  const float* bo = (const float*)d_in[8];
  char* ws = (char*)d_ws;
  unsigned short* Xb    = (unsigned short*)(ws + XB_OFF);
  unsigned short* Wqkvt = (unsigned short*)(ws + WQKV_OFF);
  unsigned short* Wot   = (unsigned short*)(ws + WO_OFF);
  unsigned short* QKV   = (unsigned short*)(ws + QKV_OFF);
  unsigned short* AOb   = (unsigned short*)(ws + AOB_OFF);
  unsigned short* Qp = QKV;
  unsigned short* Kp = QKV + PLANE;
  unsigned short* Vp = QKV + 2 * PLANE;
  float* ksum = (float*)(ws + KSUM_OFF);
  float* qsum = (float*)(ws + QSUM_OFF);
  float* qsi  = (float*)(ws + QSI_OFF);
  float* kso  = (float*)(ws + KSO_OFF);
  float* esum = (float*)(ws + ESUM_OFF);
  float* si   = (float*)(ws + SI_OFF);
  float* sa   = (float*)(ws + SA_OFF);
  float* kvp  = (float*)(ws + KVP_OFF);

  (void)hipMemsetAsync(ws + ST_OFF, 0, 81920, stream);  // zero small atomic accumulators
  conv_all_k<<<3072, 256, 0, stream>>>(x, Wq, Wk, Wv, Wo, Xb, Wqkvt, Wot);
  gemm8p<0><<<dim3(12, 64), 512, 0, stream>>>(Xb, Wqkvt, bq, bk, bv, qsum, ksum, (void*)QKV, 3072);
  flow1_k<<<NBH * 8, 256, 0, stream>>>(Qp, Kp, ksum, qsum, si, qsi, kso);
  flow2kv_k<<<NBH * 8, 256, 0, stream>>>(Qp, Kp, Vp, qsi, kso, sa, esum, kvp);
  outk_k<<<NBH * 16, 256, 0, stream>>>(Qp, kvp, esum, si, sa, AOb);
  gemm8p<1><<<dim3(4, 64), 512, 0, stream>>>(AOb, Wot, bo, nullptr, nullptr, nullptr, nullptr, d_out, 1024);
}